// Round 1
// baseline (1546.214 us; speedup 1.0000x reference)
//
#include <hip/hip_runtime.h>
#include <hip/hip_bf16.h>

#define N_TOT   150000
#define N_USER  100000
#define E_TOT   1000000
#define B_TOT   4096
#define D_DIM   64

// ---------------------------------------------------------------------------
// Per-node attention scalars: a_nb[v] = relu(x[v]@Wn+bn) . Wa[0:64]
//                             a_self[v] = relu(x[v]@Ws+bs) . Wa[64:128]
// One wave (64 lanes) per node; W matrices staged in LDS.
// ---------------------------------------------------------------------------
__global__ void node_scalars_kernel(const float* __restrict__ x,
                                    const float* __restrict__ Wn, const float* __restrict__ bn,
                                    const float* __restrict__ Ws, const float* __restrict__ bs,
                                    const float* __restrict__ Wa,
                                    float* __restrict__ a_nb, float* __restrict__ a_self,
                                    int nNodes)
{
    __shared__ float sWn[64 * 64];
    __shared__ float sWs[64 * 64];
    __shared__ float sWaT[64], sWaB[64], sbn[64], sbs[64];
    for (int i = threadIdx.x; i < 64 * 64; i += blockDim.x) { sWn[i] = Wn[i]; sWs[i] = Ws[i]; }
    if (threadIdx.x < 64) {
        sWaT[threadIdx.x] = Wa[threadIdx.x];
        sWaB[threadIdx.x] = Wa[64 + threadIdx.x];
        sbn[threadIdx.x]  = bn[threadIdx.x];
        sbs[threadIdx.x]  = bs[threadIdx.x];
    }
    __syncthreads();

    const int lane   = threadIdx.x & 63;
    const int wave   = (blockIdx.x * blockDim.x + threadIdx.x) >> 6;
    const int nWaves = (gridDim.x * blockDim.x) >> 6;

    for (int v = wave; v < nNodes; v += nWaves) {
        float xv = x[v * 64 + lane];
        float hn = sbn[lane], hs = sbs[lane];
        #pragma unroll
        for (int k = 0; k < 64; ++k) {
            float xk = __shfl(xv, k);
            hn = fmaf(xk, sWn[k * 64 + lane], hn);
            hs = fmaf(xk, sWs[k * 64 + lane], hs);
        }
        hn = fmaxf(hn, 0.0f) * sWaT[lane];
        hs = fmaxf(hs, 0.0f) * sWaB[lane];
        #pragma unroll
        for (int off = 32; off; off >>= 1) {
            hn += __shfl_xor(hn, off);
            hs += __shfl_xor(hs, off);
        }
        if (lane == 0) { a_nb[v] = hn; a_self[v] = hs; }
    }
}

// ---------------------------------------------------------------------------
// Edge pass A: mask[e], rowsum (segment_sum of mask over row), l0 partial sum
// ---------------------------------------------------------------------------
__global__ void edge_pass_a_kernel(const int* __restrict__ row, const int* __restrict__ col,
                                   const float* __restrict__ u,
                                   const float* __restrict__ a_nb, const float* __restrict__ a_self,
                                   const float* __restrict__ ba_p, const float* __restrict__ temp_p,
                                   float* __restrict__ mask, float* __restrict__ rowsum,
                                   float* __restrict__ l0_accum, int nE)
{
    const float ba   = ba_p[0];
    const float t    = temp_p[0];
    const float invt = 1.0f / t;
    const float lt   = logf(0.45f / 1.05f);   // log(-GAMMA/ZETA)
    const float shift = t * lt;

    float l0local = 0.0f;
    for (int e = blockIdx.x * blockDim.x + threadIdx.x; e < nE; e += gridDim.x * blockDim.x) {
        int r = row[e], c = col[e];
        float la = a_nb[r] + a_self[c] + ba;
        float uu = u[e];
        float noise = logf(uu) - log1pf(-uu);
        float gate  = 1.0f / (1.0f + expf(-(noise + la) * invt));
        float m = fminf(fmaxf(gate * 1.5f - 0.45f, 0.0f), 1.0f); // ZETA-GAMMA=1.5, GAMMA=-0.45
        mask[e] = m;
        if (m > 0.0f) unsafeAtomicAdd(&rowsum[r], m);
        l0local += 1.0f / (1.0f + expf(-(la - shift)));
    }

    __shared__ float red[256];
    red[threadIdx.x] = l0local;
    __syncthreads();
    for (int s = 128; s > 0; s >>= 1) {
        if (threadIdx.x < s) red[threadIdx.x] += red[threadIdx.x + s];
        __syncthreads();
    }
    if (threadIdx.x == 0) unsafeAtomicAdd(l0_accum, red[0]);
}

// ---------------------------------------------------------------------------
// rowsum -> d_inv_sqrt in place
// ---------------------------------------------------------------------------
__global__ void dis_kernel(float* __restrict__ rs, int n)
{
    int i = blockIdx.x * blockDim.x + threadIdx.x;
    if (i < n) {
        float v = rs[i] + 1e-6f;
        float d = 1.0f / sqrtf(v);
        rs[i] = fminf(d, 10.0f);
    }
}

// ---------------------------------------------------------------------------
// Edge pass B: x_next[row] += mask*dis[row]*dis[col] * x[col]
// 16 threads per edge, float4 each.
// ---------------------------------------------------------------------------
__global__ void edge_pass_b_kernel(const int* __restrict__ row, const int* __restrict__ col,
                                   const float* __restrict__ mask, const float* __restrict__ dis,
                                   const float* __restrict__ x, float* __restrict__ xn, int nE)
{
    const int stride = gridDim.x * blockDim.x;
    const int total  = nE * 16;
    for (int idx = blockIdx.x * blockDim.x + threadIdx.x; idx < total; idx += stride) {
        int e = idx >> 4;
        int q = idx & 15;
        float m = mask[e];
        if (m <= 0.0f) continue;
        int r = row[e], c = col[e];
        float val = m * dis[r] * dis[c];
        float4 xv = *reinterpret_cast<const float4*>(x + c * 64 + q * 4);
        float* dst = xn + r * 64 + q * 4;
        unsafeAtomicAdd(dst + 0, val * xv.x);
        unsafeAtomicAdd(dst + 1, val * xv.y);
        unsafeAtomicAdd(dst + 2, val * xv.z);
        unsafeAtomicAdd(dst + 3, val * xv.w);
    }
}

// ---------------------------------------------------------------------------
// BPR loss partial sum: one wave per batch element
// ---------------------------------------------------------------------------
__global__ void bpr_kernel(const float* __restrict__ f, const float* __restrict__ x1,
                           const float* __restrict__ x2,
                           const int* __restrict__ users, const int* __restrict__ items,
                           const int* __restrict__ negs,
                           float* __restrict__ bpr_accum, int B)
{
    const int lane   = threadIdx.x & 63;
    const int wave   = (blockIdx.x * blockDim.x + threadIdx.x) >> 6;
    const int nWaves = (gridDim.x * blockDim.x) >> 6;

    float local = 0.0f;
    for (int b = wave; b < B; b += nWaves) {
        int ui = users[b] * 64;
        int pi = (N_USER + items[b]) * 64;
        int ni = (N_USER + negs[b]) * 64;
        float a = f[ui + lane] + x1[ui + lane] + x2[ui + lane];
        float p = f[pi + lane] + x1[pi + lane] + x2[pi + lane];
        float n = f[ni + lane] + x1[ni + lane] + x2[ni + lane];
        float ps = a * p, ns = a * n;
        #pragma unroll
        for (int off = 32; off; off >>= 1) {
            ps += __shfl_xor(ps, off);
            ns += __shfl_xor(ns, off);
        }
        if (lane == 0) {
            float s = 1.0f / (1.0f + expf(-(ps - ns)));
            local += -logf(s + 1e-5f);
        }
    }
    if (lane == 0) unsafeAtomicAdd(bpr_accum, local);
}

// ---------------------------------------------------------------------------
// L2 regularization on params
// ---------------------------------------------------------------------------
__global__ void reg_kernel(const float* __restrict__ w0, const float* __restrict__ b0,
                           const float* __restrict__ w1, const float* __restrict__ b1,
                           const float* __restrict__ wa0, const float* __restrict__ ba0,
                           const float* __restrict__ w2, const float* __restrict__ b2,
                           const float* __restrict__ w3, const float* __restrict__ b3,
                           const float* __restrict__ wa1, const float* __restrict__ ba1,
                           float* __restrict__ accum)
{
    int t = threadIdx.x;
    float s = 0.0f;
    for (int i = t; i < 4096; i += 256)
        s += w0[i]*w0[i] + w1[i]*w1[i] + w2[i]*w2[i] + w3[i]*w3[i];
    for (int i = t; i < 64; i += 256)
        s += b0[i]*b0[i] + b1[i]*b1[i] + b2[i]*b2[i] + b3[i]*b3[i];
    for (int i = t; i < 128; i += 256)
        s += wa0[i]*wa0[i] + wa1[i]*wa1[i];
    if (t == 0) s += ba0[0]*ba0[0] + ba1[0]*ba1[0];

    __shared__ float red[256];
    red[t] = s;
    __syncthreads();
    for (int st = 128; st > 0; st >>= 1) {
        if (t < st) red[t] += red[t + st];
        __syncthreads();
    }
    if (t == 0) accum[0] = red[0];
}

// ---------------------------------------------------------------------------
// Final combine: bpr + reg + l0
// ---------------------------------------------------------------------------
__global__ void finalize_kernel(const float* __restrict__ scal, float* __restrict__ out)
{
    // scal[0]=bpr_sum, scal[1]=reg_sumsq, scal[2]=l0 sum layer0, scal[3]=l0 sum layer1
    float bpr = scal[0] / (float)B_TOT;
    float reg = scal[1] * 1e-4f;
    float l0  = (scal[2] + scal[3]) * (1e-4f / (float)E_TOT);
    out[0] = bpr + reg + l0;
}

extern "C" void kernel_launch(void* const* d_in, const int* in_sizes, int n_in,
                              void* d_out, int out_size, void* d_ws, size_t ws_size,
                              hipStream_t stream)
{
    const float* features = (const float*)d_in[0];
    const int*   row      = (const int*)d_in[1];
    const int*   col      = (const int*)d_in[2];
    const int*   users    = (const int*)d_in[3];
    const int*   items    = (const int*)d_in[4];
    const int*   negs     = (const int*)d_in[5];
    const float* u0       = (const float*)d_in[6];
    const float* u1       = (const float*)d_in[7];
    const float* temp     = (const float*)d_in[8];
    const float* W_nb0    = (const float*)d_in[9];
    const float* b_nb0    = (const float*)d_in[10];
    const float* W_self0  = (const float*)d_in[11];
    const float* b_self0  = (const float*)d_in[12];
    const float* W_att0   = (const float*)d_in[13];
    const float* b_att0   = (const float*)d_in[14];
    const float* W_nb1    = (const float*)d_in[15];
    const float* b_nb1    = (const float*)d_in[16];
    const float* W_self1  = (const float*)d_in[17];
    const float* b_self1  = (const float*)d_in[18];
    const float* W_att1   = (const float*)d_in[19];
    const float* b_att1   = (const float*)d_in[20];
    float* out = (float*)d_out;

    // Workspace layout (floats):
    float* ws      = (float*)d_ws;
    float* x1      = ws;                       // N*D = 9,600,000
    float* x2      = x1 + (size_t)N_TOT * 64;  // 9,600,000
    float* rowsum  = x2 + (size_t)N_TOT * 64;  // 150,000 (also holds d_inv_sqrt)
    float* scal    = rowsum + N_TOT;           // 16
    float* a_nb    = scal + 16;                // 150,000
    float* a_self  = a_nb + N_TOT;             // 150,000
    float* mask    = a_self + N_TOT;           // 1,000,000
    // total ~82.6 MB

    // Zero x1, x2, rowsum, scalars in one contiguous memset
    size_t zero_bytes = ((size_t)N_TOT * 64 * 2 + N_TOT + 16) * sizeof(float);
    hipMemsetAsync(x1, 0, zero_bytes, stream);

    const int nDisBlocks = (N_TOT + 255) / 256;

    // ---- Layer 0 ----
    node_scalars_kernel<<<1024, 256, 0, stream>>>(features, W_nb0, b_nb0, W_self0, b_self0,
                                                  W_att0, a_nb, a_self, N_TOT);
    edge_pass_a_kernel<<<2048, 256, 0, stream>>>(row, col, u0, a_nb, a_self, b_att0, temp,
                                                 mask, rowsum, &scal[2], E_TOT);
    dis_kernel<<<nDisBlocks, 256, 0, stream>>>(rowsum, N_TOT);
    edge_pass_b_kernel<<<4096, 256, 0, stream>>>(row, col, mask, rowsum, features, x1, E_TOT);

    // ---- Layer 1 ----
    hipMemsetAsync(rowsum, 0, (size_t)N_TOT * sizeof(float), stream);
    node_scalars_kernel<<<1024, 256, 0, stream>>>(x1, W_nb1, b_nb1, W_self1, b_self1,
                                                  W_att1, a_nb, a_self, N_TOT);
    edge_pass_a_kernel<<<2048, 256, 0, stream>>>(row, col, u1, a_nb, a_self, b_att1, temp,
                                                 mask, rowsum, &scal[3], E_TOT);
    dis_kernel<<<nDisBlocks, 256, 0, stream>>>(rowsum, N_TOT);
    edge_pass_b_kernel<<<4096, 256, 0, stream>>>(row, col, mask, rowsum, x1, x2, E_TOT);

    // ---- Losses ----
    bpr_kernel<<<64, 256, 0, stream>>>(features, x1, x2, users, items, negs, &scal[0], B_TOT);
    reg_kernel<<<1, 256, 0, stream>>>(W_nb0, b_nb0, W_self0, b_self0, W_att0, b_att0,
                                      W_nb1, b_nb1, W_self1, b_self1, W_att1, b_att1, &scal[1]);
    finalize_kernel<<<1, 1, 0, stream>>>(scal, out);
}

// Round 2
// 947.906 us; speedup vs baseline: 1.6312x; 1.6312x over previous
//
#include <hip/hip_runtime.h>
#include <hip/hip_bf16.h>

#define N_TOT   150000
#define N_USER  100000
#define E_TOT   1000000
#define B_TOT   4096
#define D_DIM   64

#define NSCAN       (N_TOT + 1)
#define SCAN_CHUNK  1024
#define SCAN_BLOCKS ((NSCAN + SCAN_CHUNK - 1) / SCAN_CHUNK)   // 147

// ---------------------------------------------------------------------------
// Per-node attention scalars: a_nb[v] = relu(x[v]@Wn+bn) . Wa[0:64]
//                             a_self[v] = relu(x[v]@Ws+bs) . Wa[64:128]
// One wave per node; W matrices staged in LDS.
// ---------------------------------------------------------------------------
__global__ void node_scalars_kernel(const float* __restrict__ x,
                                    const float* __restrict__ Wn, const float* __restrict__ bn,
                                    const float* __restrict__ Ws, const float* __restrict__ bs,
                                    const float* __restrict__ Wa,
                                    float* __restrict__ a_nb, float* __restrict__ a_self,
                                    int nNodes)
{
    __shared__ float sWn[64 * 64];
    __shared__ float sWs[64 * 64];
    __shared__ float sWaT[64], sWaB[64], sbn[64], sbs[64];
    for (int i = threadIdx.x; i < 64 * 64; i += blockDim.x) { sWn[i] = Wn[i]; sWs[i] = Ws[i]; }
    if (threadIdx.x < 64) {
        sWaT[threadIdx.x] = Wa[threadIdx.x];
        sWaB[threadIdx.x] = Wa[64 + threadIdx.x];
        sbn[threadIdx.x]  = bn[threadIdx.x];
        sbs[threadIdx.x]  = bs[threadIdx.x];
    }
    __syncthreads();

    const int lane   = threadIdx.x & 63;
    const int wave   = (blockIdx.x * blockDim.x + threadIdx.x) >> 6;
    const int nWaves = (gridDim.x * blockDim.x) >> 6;

    for (int v = wave; v < nNodes; v += nWaves) {
        float xv = x[v * 64 + lane];
        float hn = sbn[lane], hs = sbs[lane];
        #pragma unroll
        for (int k = 0; k < 64; ++k) {
            float xk = __shfl(xv, k);
            hn = fmaf(xk, sWn[k * 64 + lane], hn);
            hs = fmaf(xk, sWs[k * 64 + lane], hs);
        }
        hn = fmaxf(hn, 0.0f) * sWaT[lane];
        hs = fmaxf(hs, 0.0f) * sWaB[lane];
        #pragma unroll
        for (int off = 32; off; off >>= 1) {
            hn += __shfl_xor(hn, off);
            hs += __shfl_xor(hs, off);
        }
        if (lane == 0) { a_nb[v] = hn; a_self[v] = hs; }
    }
}

// ---------------------------------------------------------------------------
// CSR build: histogram of row[]
// ---------------------------------------------------------------------------
__global__ void hist_kernel(const int* __restrict__ row, int* __restrict__ count, int nE)
{
    for (int e = blockIdx.x * blockDim.x + threadIdx.x; e < nE; e += gridDim.x * blockDim.x)
        atomicAdd(&count[row[e]], 1);
}

__global__ void scan_phase1(const int* __restrict__ count, int* __restrict__ blockSums)
{
    __shared__ int red[256];
    int base = blockIdx.x * SCAN_CHUNK;
    int s = 0;
    for (int i = threadIdx.x; i < SCAN_CHUNK; i += 256) {
        int idx = base + i;
        s += (idx < NSCAN) ? count[idx] : 0;
    }
    red[threadIdx.x] = s;
    __syncthreads();
    for (int st = 128; st > 0; st >>= 1) {
        if (threadIdx.x < st) red[threadIdx.x] += red[threadIdx.x + st];
        __syncthreads();
    }
    if (threadIdx.x == 0) blockSums[blockIdx.x] = red[0];
}

__global__ void scan_phase2(int* __restrict__ blockSums, int n)
{
    __shared__ int sh[256];
    int t = threadIdx.x;
    int v = (t < n) ? blockSums[t] : 0;
    sh[t] = v;
    __syncthreads();
    for (int off = 1; off < 256; off <<= 1) {
        int x = sh[t];
        if (t >= off) x += sh[t - off];
        __syncthreads();
        sh[t] = x;
        __syncthreads();
    }
    if (t < n) blockSums[t] = sh[t] - v;   // exclusive
}

__global__ void scan_phase3(const int* __restrict__ count, const int* __restrict__ blockSums,
                            int* __restrict__ start, int* __restrict__ cursor)
{
    __shared__ int sh[256];
    int base = blockIdx.x * SCAN_CHUNK;
    int t = threadIdx.x;
    int v[4];
    int s = 0;
    #pragma unroll
    for (int k = 0; k < 4; ++k) {
        int idx = base + t * 4 + k;
        v[k] = (idx < NSCAN) ? count[idx] : 0;
        s += v[k];
    }
    int orig = s;
    sh[t] = s;
    __syncthreads();
    for (int off = 1; off < 256; off <<= 1) {
        int x = sh[t];
        if (t >= off) x += sh[t - off];
        __syncthreads();
        sh[t] = x;
        __syncthreads();
    }
    int pre = sh[t] - orig + blockSums[blockIdx.x];
    #pragma unroll
    for (int k = 0; k < 4; ++k) {
        int idx = base + t * 4 + k;
        if (idx < NSCAN) { start[idx] = pre; cursor[idx] = pre; }
        pre += v[k];
    }
}

__global__ void scatter_kernel(const int* __restrict__ row, int* __restrict__ cursor,
                               int* __restrict__ edge_idx, int nE)
{
    for (int e = blockIdx.x * blockDim.x + threadIdx.x; e < nE; e += gridDim.x * blockDim.x) {
        int pos = atomicAdd(&cursor[row[e]], 1);
        edge_idx[pos] = e;
    }
}

// ---------------------------------------------------------------------------
// Edge pass A: mask[e], rowsum (segment_sum of mask over row), l0 partial sum
// ---------------------------------------------------------------------------
__global__ void edge_pass_a_kernel(const int* __restrict__ row, const int* __restrict__ col,
                                   const float* __restrict__ u,
                                   const float* __restrict__ a_nb, const float* __restrict__ a_self,
                                   const float* __restrict__ ba_p, const float* __restrict__ temp_p,
                                   float* __restrict__ mask, float* __restrict__ rowsum,
                                   float* __restrict__ l0_accum, int nE)
{
    const float ba   = ba_p[0];
    const float t    = temp_p[0];
    const float invt = 1.0f / t;
    const float lt   = logf(0.45f / 1.05f);   // log(-GAMMA/ZETA)
    const float shift = t * lt;

    float l0local = 0.0f;
    for (int e = blockIdx.x * blockDim.x + threadIdx.x; e < nE; e += gridDim.x * blockDim.x) {
        int r = row[e], c = col[e];
        float la = a_nb[r] + a_self[c] + ba;
        float uu = u[e];
        float noise = logf(uu) - log1pf(-uu);
        float gate  = 1.0f / (1.0f + expf(-(noise + la) * invt));
        float m = fminf(fmaxf(gate * 1.5f - 0.45f, 0.0f), 1.0f); // ZETA-GAMMA=1.5, GAMMA=-0.45
        mask[e] = m;
        if (m > 0.0f) unsafeAtomicAdd(&rowsum[r], m);
        l0local += 1.0f / (1.0f + expf(-(la - shift)));
    }

    __shared__ float red[256];
    red[threadIdx.x] = l0local;
    __syncthreads();
    for (int s = 128; s > 0; s >>= 1) {
        if (threadIdx.x < s) red[threadIdx.x] += red[threadIdx.x + s];
        __syncthreads();
    }
    if (threadIdx.x == 0) unsafeAtomicAdd(l0_accum, red[0]);
}

// ---------------------------------------------------------------------------
// rowsum -> d_inv_sqrt in place
// ---------------------------------------------------------------------------
__global__ void dis_kernel(float* __restrict__ rs, int n)
{
    int i = blockIdx.x * blockDim.x + threadIdx.x;
    if (i < n) {
        float v = rs[i] + 1e-6f;
        float d = 1.0f / sqrtf(v);
        rs[i] = fminf(d, 10.0f);
    }
}

// ---------------------------------------------------------------------------
// Edge gather: xn[r] = dis[r] * sum_{e in bucket(r)} mask[e]*dis[col]*x[col]
// One wave per node, lane = feature dim. No atomics, single write per row.
// ---------------------------------------------------------------------------
__global__ void edge_gather_kernel(const int* __restrict__ col, const int* __restrict__ edge_idx,
                                   const int* __restrict__ start,
                                   const float* __restrict__ mask, const float* __restrict__ dis,
                                   const float* __restrict__ x, float* __restrict__ xn, int nNodes)
{
    const int lane   = threadIdx.x & 63;
    const int wave   = (blockIdx.x * blockDim.x + threadIdx.x) >> 6;
    const int nWaves = (gridDim.x * blockDim.x) >> 6;

    for (int r = wave; r < nNodes; r += nWaves) {
        int js = start[r], je = start[r + 1];
        float acc = 0.0f;
        for (int j = js; j < je; ++j) {
            int e = edge_idx[j];
            float m = mask[e];
            if (m > 0.0f) {
                int c = col[e];
                acc = fmaf(m * dis[c], x[c * 64 + lane], acc);
            }
        }
        xn[r * 64 + lane] = acc * dis[r];
    }
}

// ---------------------------------------------------------------------------
// BPR loss partial sum: one wave per batch element
// ---------------------------------------------------------------------------
__global__ void bpr_kernel(const float* __restrict__ f, const float* __restrict__ x1,
                           const float* __restrict__ x2,
                           const int* __restrict__ users, const int* __restrict__ items,
                           const int* __restrict__ negs,
                           float* __restrict__ bpr_accum, int B)
{
    const int lane   = threadIdx.x & 63;
    const int wave   = (blockIdx.x * blockDim.x + threadIdx.x) >> 6;
    const int nWaves = (gridDim.x * blockDim.x) >> 6;

    float local = 0.0f;
    for (int b = wave; b < B; b += nWaves) {
        int ui = users[b] * 64;
        int pi = (N_USER + items[b]) * 64;
        int ni = (N_USER + negs[b]) * 64;
        float a = f[ui + lane] + x1[ui + lane] + x2[ui + lane];
        float p = f[pi + lane] + x1[pi + lane] + x2[pi + lane];
        float n = f[ni + lane] + x1[ni + lane] + x2[ni + lane];
        float ps = a * p, ns = a * n;
        #pragma unroll
        for (int off = 32; off; off >>= 1) {
            ps += __shfl_xor(ps, off);
            ns += __shfl_xor(ns, off);
        }
        if (lane == 0) {
            float s = 1.0f / (1.0f + expf(-(ps - ns)));
            local += -logf(s + 1e-5f);
        }
    }
    if (lane == 0) unsafeAtomicAdd(bpr_accum, local);
}

// ---------------------------------------------------------------------------
// L2 regularization on params
// ---------------------------------------------------------------------------
__global__ void reg_kernel(const float* __restrict__ w0, const float* __restrict__ b0,
                           const float* __restrict__ w1, const float* __restrict__ b1,
                           const float* __restrict__ wa0, const float* __restrict__ ba0,
                           const float* __restrict__ w2, const float* __restrict__ b2,
                           const float* __restrict__ w3, const float* __restrict__ b3,
                           const float* __restrict__ wa1, const float* __restrict__ ba1,
                           float* __restrict__ accum)
{
    int t = threadIdx.x;
    float s = 0.0f;
    for (int i = t; i < 4096; i += 256)
        s += w0[i]*w0[i] + w1[i]*w1[i] + w2[i]*w2[i] + w3[i]*w3[i];
    for (int i = t; i < 64; i += 256)
        s += b0[i]*b0[i] + b1[i]*b1[i] + b2[i]*b2[i] + b3[i]*b3[i];
    for (int i = t; i < 128; i += 256)
        s += wa0[i]*wa0[i] + wa1[i]*wa1[i];
    if (t == 0) s += ba0[0]*ba0[0] + ba1[0]*ba1[0];

    __shared__ float red[256];
    red[t] = s;
    __syncthreads();
    for (int st = 128; st > 0; st >>= 1) {
        if (t < st) red[t] += red[t + st];
        __syncthreads();
    }
    if (t == 0) accum[0] = red[0];
}

// ---------------------------------------------------------------------------
// Final combine: bpr + reg + l0
// ---------------------------------------------------------------------------
__global__ void finalize_kernel(const float* __restrict__ scal, float* __restrict__ out)
{
    float bpr = scal[0] / (float)B_TOT;
    float reg = scal[1] * 1e-4f;
    float l0  = (scal[2] + scal[3]) * (1e-4f / (float)E_TOT);
    out[0] = bpr + reg + l0;
}

extern "C" void kernel_launch(void* const* d_in, const int* in_sizes, int n_in,
                              void* d_out, int out_size, void* d_ws, size_t ws_size,
                              hipStream_t stream)
{
    const float* features = (const float*)d_in[0];
    const int*   row      = (const int*)d_in[1];
    const int*   col      = (const int*)d_in[2];
    const int*   users    = (const int*)d_in[3];
    const int*   items    = (const int*)d_in[4];
    const int*   negs     = (const int*)d_in[5];
    const float* u0       = (const float*)d_in[6];
    const float* u1       = (const float*)d_in[7];
    const float* temp     = (const float*)d_in[8];
    const float* W_nb0    = (const float*)d_in[9];
    const float* b_nb0    = (const float*)d_in[10];
    const float* b_att0   = (const float*)d_in[14];
    const float* W_self0  = (const float*)d_in[11];
    const float* b_self0  = (const float*)d_in[12];
    const float* W_att0   = (const float*)d_in[13];
    const float* W_nb1    = (const float*)d_in[15];
    const float* b_nb1    = (const float*)d_in[16];
    const float* W_self1  = (const float*)d_in[17];
    const float* b_self1  = (const float*)d_in[18];
    const float* W_att1   = (const float*)d_in[19];
    const float* b_att1   = (const float*)d_in[20];
    float* out = (float*)d_out;

    // ---- Workspace layout (element offsets) ----
    float* ws = (float*)d_ws;
    float* x1      = ws;                          // N*64 = 9,600,000 f
    float* x2      = x1 + (size_t)N_TOT * 64;     // 9,600,000 f
    // zeroed block starts here:
    int*   count   = (int*)(x2 + (size_t)N_TOT * 64);  // NSCAN ints
    float* rowsum0 = (float*)(count + NSCAN);     // N_TOT f
    float* rowsum1 = rowsum0 + N_TOT;             // N_TOT f
    float* scal    = rowsum1 + N_TOT;             // 16 f
    // zeroed block ends here
    int*   start   = (int*)(scal + 16);           // NSCAN ints
    int*   cursor  = start + NSCAN;               // NSCAN ints
    int*   blockSums = cursor + NSCAN;            // SCAN_BLOCKS ints (pad 1024)
    int*   edge_idx  = blockSums + 1024;          // E ints
    float* mask    = (float*)(edge_idx + E_TOT);  // E f
    float* a_nb    = mask + E_TOT;                // N_TOT f
    float* a_self  = a_nb + N_TOT;                // N_TOT f

    // Zero count + rowsum0 + rowsum1 + scal in one memset (~1.8MB)
    size_t zero_bytes = ((size_t)NSCAN + N_TOT + N_TOT + 16) * 4;
    hipMemsetAsync(count, 0, zero_bytes, stream);

    const int nDisBlocks = (N_TOT + 255) / 256;

    // ---- CSR build (row/col shared by both layers) ----
    hist_kernel<<<1024, 256, 0, stream>>>(row, count, E_TOT);
    scan_phase1<<<SCAN_BLOCKS, 256, 0, stream>>>(count, blockSums);
    scan_phase2<<<1, 256, 0, stream>>>(blockSums, SCAN_BLOCKS);
    scan_phase3<<<SCAN_BLOCKS, 256, 0, stream>>>(count, blockSums, start, cursor);
    scatter_kernel<<<1024, 256, 0, stream>>>(row, cursor, edge_idx, E_TOT);

    // ---- Layer 0 ----
    node_scalars_kernel<<<1024, 256, 0, stream>>>(features, W_nb0, b_nb0, W_self0, b_self0,
                                                  W_att0, a_nb, a_self, N_TOT);
    edge_pass_a_kernel<<<2048, 256, 0, stream>>>(row, col, u0, a_nb, a_self, b_att0, temp,
                                                 mask, rowsum0, &scal[2], E_TOT);
    dis_kernel<<<nDisBlocks, 256, 0, stream>>>(rowsum0, N_TOT);
    edge_gather_kernel<<<2048, 256, 0, stream>>>(col, edge_idx, start, mask, rowsum0,
                                                 features, x1, N_TOT);

    // ---- Layer 1 ----
    node_scalars_kernel<<<1024, 256, 0, stream>>>(x1, W_nb1, b_nb1, W_self1, b_self1,
                                                  W_att1, a_nb, a_self, N_TOT);
    edge_pass_a_kernel<<<2048, 256, 0, stream>>>(row, col, u1, a_nb, a_self, b_att1, temp,
                                                 mask, rowsum1, &scal[3], E_TOT);
    dis_kernel<<<nDisBlocks, 256, 0, stream>>>(rowsum1, N_TOT);
    edge_gather_kernel<<<2048, 256, 0, stream>>>(col, edge_idx, start, mask, rowsum1,
                                                 x1, x2, N_TOT);

    // ---- Losses ----
    bpr_kernel<<<64, 256, 0, stream>>>(features, x1, x2, users, items, negs, &scal[0], B_TOT);
    reg_kernel<<<1, 256, 0, stream>>>(W_nb0, b_nb0, W_self0, b_self0, W_att0, b_att0,
                                      W_nb1, b_nb1, W_self1, b_self1, W_att1, b_att1, &scal[1]);
    finalize_kernel<<<1, 1, 0, stream>>>(scal, out);
}

// Round 3
// 753.698 us; speedup vs baseline: 2.0515x; 1.2577x over previous
//
#include <hip/hip_runtime.h>
#include <hip/hip_bf16.h>

#define N_TOT   150000
#define N_USER  100000
#define E_TOT   1000000
#define B_TOT   4096
#define D_DIM   64

#define NSCAN       (N_TOT + 1)
#define SCAN_CHUNK  1024
#define SCAN_BLOCKS ((NSCAN + SCAN_CHUNK - 1) / SCAN_CHUNK)   // 147

// ---------------------------------------------------------------------------
// Per-node attention scalars: a_nb[v] = relu(x[v]@Wn+bn) . Wa[0:64]
//                             a_self[v] = relu(x[v]@Ws+bs) . Wa[64:128]
// One wave per node. Weight COLUMNS live in VGPRs (wn[k] = Wn[k][lane]);
// the node's x-row is read through a wave-uniform pointer (readfirstlane)
// so loads go down the scalar/broadcast path. DS pipe nearly idle.
// ---------------------------------------------------------------------------
__global__ __launch_bounds__(256, 3)
void node_scalars_kernel(const float* __restrict__ x,
                         const float* __restrict__ Wn, const float* __restrict__ bn,
                         const float* __restrict__ Ws, const float* __restrict__ bs,
                         const float* __restrict__ Wa,
                         float* __restrict__ a_nb, float* __restrict__ a_self,
                         int nNodes)
{
    const int lane   = threadIdx.x & 63;
    const int wave   = (blockIdx.x * blockDim.x + threadIdx.x) >> 6;
    const int nWaves = (gridDim.x * blockDim.x) >> 6;

    // Per-lane weight columns (compile-time indexed -> stay in VGPRs)
    float wn[64], wsr[64];
    #pragma unroll
    for (int k = 0; k < 64; ++k) wn[k]  = Wn[k * 64 + lane];
    #pragma unroll
    for (int k = 0; k < 64; ++k) wsr[k] = Ws[k * 64 + lane];
    const float waT = Wa[lane];
    const float waB = Wa[64 + lane];
    const float bnl = bn[lane];
    const float bsl = bs[lane];

    for (int v = wave; v < nNodes; v += nWaves) {
        const int vu = __builtin_amdgcn_readfirstlane(v);
        const float* __restrict__ xr = x + (size_t)vu * 64;
        float hn = bnl, hs = bsl;
        #pragma unroll
        for (int k = 0; k < 64; ++k) {
            float xk = xr[k];                 // wave-uniform -> scalar/broadcast load
            hn = fmaf(xk, wn[k],  hn);
            hs = fmaf(xk, wsr[k], hs);
        }
        hn = fmaxf(hn, 0.0f) * waT;
        hs = fmaxf(hs, 0.0f) * waB;
        #pragma unroll
        for (int off = 32; off; off >>= 1) {
            hn += __shfl_xor(hn, off);
            hs += __shfl_xor(hs, off);
        }
        if (lane == 0) { a_nb[vu] = hn; a_self[vu] = hs; }
    }
}

// ---------------------------------------------------------------------------
// CSR build: histogram of row[]
// ---------------------------------------------------------------------------
__global__ void hist_kernel(const int* __restrict__ row, int* __restrict__ count, int nE)
{
    for (int e = blockIdx.x * blockDim.x + threadIdx.x; e < nE; e += gridDim.x * blockDim.x)
        atomicAdd(&count[row[e]], 1);
}

__global__ void scan_phase1(const int* __restrict__ count, int* __restrict__ blockSums)
{
    __shared__ int red[256];
    int base = blockIdx.x * SCAN_CHUNK;
    int s = 0;
    for (int i = threadIdx.x; i < SCAN_CHUNK; i += 256) {
        int idx = base + i;
        s += (idx < NSCAN) ? count[idx] : 0;
    }
    red[threadIdx.x] = s;
    __syncthreads();
    for (int st = 128; st > 0; st >>= 1) {
        if (threadIdx.x < st) red[threadIdx.x] += red[threadIdx.x + st];
        __syncthreads();
    }
    if (threadIdx.x == 0) blockSums[blockIdx.x] = red[0];
}

__global__ void scan_phase2(int* __restrict__ blockSums, int n)
{
    __shared__ int sh[256];
    int t = threadIdx.x;
    int v = (t < n) ? blockSums[t] : 0;
    sh[t] = v;
    __syncthreads();
    for (int off = 1; off < 256; off <<= 1) {
        int x = sh[t];
        if (t >= off) x += sh[t - off];
        __syncthreads();
        sh[t] = x;
        __syncthreads();
    }
    if (t < n) blockSums[t] = sh[t] - v;   // exclusive
}

__global__ void scan_phase3(const int* __restrict__ count, const int* __restrict__ blockSums,
                            int* __restrict__ start, int* __restrict__ cursor)
{
    __shared__ int sh[256];
    int base = blockIdx.x * SCAN_CHUNK;
    int t = threadIdx.x;
    int v[4];
    int s = 0;
    #pragma unroll
    for (int k = 0; k < 4; ++k) {
        int idx = base + t * 4 + k;
        v[k] = (idx < NSCAN) ? count[idx] : 0;
        s += v[k];
    }
    int orig = s;
    sh[t] = s;
    __syncthreads();
    for (int off = 1; off < 256; off <<= 1) {
        int x = sh[t];
        if (t >= off) x += sh[t - off];
        __syncthreads();
        sh[t] = x;
        __syncthreads();
    }
    int pre = sh[t] - orig + blockSums[blockIdx.x];
    #pragma unroll
    for (int k = 0; k < 4; ++k) {
        int idx = base + t * 4 + k;
        if (idx < NSCAN) { start[idx] = pre; cursor[idx] = pre; }
        pre += v[k];
    }
}

__global__ void scatter_kernel(const int* __restrict__ row, int* __restrict__ cursor,
                               int* __restrict__ edge_idx, int nE)
{
    for (int e = blockIdx.x * blockDim.x + threadIdx.x; e < nE; e += gridDim.x * blockDim.x) {
        int pos = atomicAdd(&cursor[row[e]], 1);
        edge_idx[pos] = e;
    }
}

// ---------------------------------------------------------------------------
// Edge pass A: mask[e], rowsum (segment_sum of mask over row), l0 partial sum
// ---------------------------------------------------------------------------
__global__ void edge_pass_a_kernel(const int* __restrict__ row, const int* __restrict__ col,
                                   const float* __restrict__ u,
                                   const float* __restrict__ a_nb, const float* __restrict__ a_self,
                                   const float* __restrict__ ba_p, const float* __restrict__ temp_p,
                                   float* __restrict__ mask, float* __restrict__ rowsum,
                                   float* __restrict__ l0_accum, int nE)
{
    const float ba   = ba_p[0];
    const float t    = temp_p[0];
    const float invt = 1.0f / t;
    const float lt   = logf(0.45f / 1.05f);   // log(-GAMMA/ZETA)
    const float shift = t * lt;

    float l0local = 0.0f;
    for (int e = blockIdx.x * blockDim.x + threadIdx.x; e < nE; e += gridDim.x * blockDim.x) {
        int r = row[e], c = col[e];
        float la = a_nb[r] + a_self[c] + ba;
        float uu = u[e];
        float noise = logf(uu) - log1pf(-uu);
        float gate  = 1.0f / (1.0f + expf(-(noise + la) * invt));
        float m = fminf(fmaxf(gate * 1.5f - 0.45f, 0.0f), 1.0f); // ZETA-GAMMA=1.5, GAMMA=-0.45
        mask[e] = m;
        if (m > 0.0f) unsafeAtomicAdd(&rowsum[r], m);
        l0local += 1.0f / (1.0f + expf(-(la - shift)));
    }

    __shared__ float red[256];
    red[threadIdx.x] = l0local;
    __syncthreads();
    for (int s = 128; s > 0; s >>= 1) {
        if (threadIdx.x < s) red[threadIdx.x] += red[threadIdx.x + s];
        __syncthreads();
    }
    if (threadIdx.x == 0) unsafeAtomicAdd(l0_accum, red[0]);
}

// ---------------------------------------------------------------------------
// rowsum -> d_inv_sqrt in place
// ---------------------------------------------------------------------------
__global__ void dis_kernel(float* __restrict__ rs, int n)
{
    int i = blockIdx.x * blockDim.x + threadIdx.x;
    if (i < n) {
        float v = rs[i] + 1e-6f;
        float d = 1.0f / sqrtf(v);
        rs[i] = fminf(d, 10.0f);
    }
}

// ---------------------------------------------------------------------------
// Edge gather: xn[r] = dis[r] * sum_{e in bucket(r)} mask[e]*dis[col]*x[col]
// One wave per node, lane = feature dim. No atomics, single write per row.
// ---------------------------------------------------------------------------
__global__ void edge_gather_kernel(const int* __restrict__ col, const int* __restrict__ edge_idx,
                                   const int* __restrict__ start,
                                   const float* __restrict__ mask, const float* __restrict__ dis,
                                   const float* __restrict__ x, float* __restrict__ xn, int nNodes)
{
    const int lane   = threadIdx.x & 63;
    const int wave   = (blockIdx.x * blockDim.x + threadIdx.x) >> 6;
    const int nWaves = (gridDim.x * blockDim.x) >> 6;

    for (int r = wave; r < nNodes; r += nWaves) {
        int js = start[r], je = start[r + 1];
        float acc = 0.0f;
        for (int j = js; j < je; ++j) {
            int e = edge_idx[j];
            float m = mask[e];
            if (m > 0.0f) {
                int c = col[e];
                acc = fmaf(m * dis[c], x[c * 64 + lane], acc);
            }
        }
        xn[r * 64 + lane] = acc * dis[r];
    }
}

// ---------------------------------------------------------------------------
// BPR loss partial sum: one wave per batch element
// ---------------------------------------------------------------------------
__global__ void bpr_kernel(const float* __restrict__ f, const float* __restrict__ x1,
                           const float* __restrict__ x2,
                           const int* __restrict__ users, const int* __restrict__ items,
                           const int* __restrict__ negs,
                           float* __restrict__ bpr_accum, int B)
{
    const int lane   = threadIdx.x & 63;
    const int wave   = (blockIdx.x * blockDim.x + threadIdx.x) >> 6;
    const int nWaves = (gridDim.x * blockDim.x) >> 6;

    float local = 0.0f;
    for (int b = wave; b < B; b += nWaves) {
        int ui = users[b] * 64;
        int pi = (N_USER + items[b]) * 64;
        int ni = (N_USER + negs[b]) * 64;
        float a = f[ui + lane] + x1[ui + lane] + x2[ui + lane];
        float p = f[pi + lane] + x1[pi + lane] + x2[pi + lane];
        float n = f[ni + lane] + x1[ni + lane] + x2[ni + lane];
        float ps = a * p, ns = a * n;
        #pragma unroll
        for (int off = 32; off; off >>= 1) {
            ps += __shfl_xor(ps, off);
            ns += __shfl_xor(ns, off);
        }
        if (lane == 0) {
            float s = 1.0f / (1.0f + expf(-(ps - ns)));
            local += -logf(s + 1e-5f);
        }
    }
    if (lane == 0) unsafeAtomicAdd(bpr_accum, local);
}

// ---------------------------------------------------------------------------
// L2 regularization on params
// ---------------------------------------------------------------------------
__global__ void reg_kernel(const float* __restrict__ w0, const float* __restrict__ b0,
                           const float* __restrict__ w1, const float* __restrict__ b1,
                           const float* __restrict__ wa0, const float* __restrict__ ba0,
                           const float* __restrict__ w2, const float* __restrict__ b2,
                           const float* __restrict__ w3, const float* __restrict__ b3,
                           const float* __restrict__ wa1, const float* __restrict__ ba1,
                           float* __restrict__ accum)
{
    int t = threadIdx.x;
    float s = 0.0f;
    for (int i = t; i < 4096; i += 256)
        s += w0[i]*w0[i] + w1[i]*w1[i] + w2[i]*w2[i] + w3[i]*w3[i];
    for (int i = t; i < 64; i += 256)
        s += b0[i]*b0[i] + b1[i]*b1[i] + b2[i]*b2[i] + b3[i]*b3[i];
    for (int i = t; i < 128; i += 256)
        s += wa0[i]*wa0[i] + wa1[i]*wa1[i];
    if (t == 0) s += ba0[0]*ba0[0] + ba1[0]*ba1[0];

    __shared__ float red[256];
    red[t] = s;
    __syncthreads();
    for (int st = 128; st > 0; st >>= 1) {
        if (t < st) red[t] += red[t + st];
        __syncthreads();
    }
    if (t == 0) accum[0] = red[0];
}

// ---------------------------------------------------------------------------
// Final combine: bpr + reg + l0
// ---------------------------------------------------------------------------
__global__ void finalize_kernel(const float* __restrict__ scal, float* __restrict__ out)
{
    float bpr = scal[0] / (float)B_TOT;
    float reg = scal[1] * 1e-4f;
    float l0  = (scal[2] + scal[3]) * (1e-4f / (float)E_TOT);
    out[0] = bpr + reg + l0;
}

extern "C" void kernel_launch(void* const* d_in, const int* in_sizes, int n_in,
                              void* d_out, int out_size, void* d_ws, size_t ws_size,
                              hipStream_t stream)
{
    const float* features = (const float*)d_in[0];
    const int*   row      = (const int*)d_in[1];
    const int*   col      = (const int*)d_in[2];
    const int*   users    = (const int*)d_in[3];
    const int*   items    = (const int*)d_in[4];
    const int*   negs     = (const int*)d_in[5];
    const float* u0       = (const float*)d_in[6];
    const float* u1       = (const float*)d_in[7];
    const float* temp     = (const float*)d_in[8];
    const float* W_nb0    = (const float*)d_in[9];
    const float* b_nb0    = (const float*)d_in[10];
    const float* W_self0  = (const float*)d_in[11];
    const float* b_self0  = (const float*)d_in[12];
    const float* W_att0   = (const float*)d_in[13];
    const float* b_att0   = (const float*)d_in[14];
    const float* W_nb1    = (const float*)d_in[15];
    const float* b_nb1    = (const float*)d_in[16];
    const float* W_self1  = (const float*)d_in[17];
    const float* b_self1  = (const float*)d_in[18];
    const float* W_att1   = (const float*)d_in[19];
    const float* b_att1   = (const float*)d_in[20];
    float* out = (float*)d_out;

    // ---- Workspace layout (element offsets) ----
    float* ws = (float*)d_ws;
    float* x1      = ws;                          // N*64 = 9,600,000 f
    float* x2      = x1 + (size_t)N_TOT * 64;     // 9,600,000 f
    // zeroed block starts here:
    int*   count   = (int*)(x2 + (size_t)N_TOT * 64);  // NSCAN ints
    float* rowsum0 = (float*)(count + NSCAN);     // N_TOT f
    float* rowsum1 = rowsum0 + N_TOT;             // N_TOT f
    float* scal    = rowsum1 + N_TOT;             // 16 f
    // zeroed block ends here
    int*   start   = (int*)(scal + 16);           // NSCAN ints
    int*   cursor  = start + NSCAN;               // NSCAN ints
    int*   blockSums = cursor + NSCAN;            // SCAN_BLOCKS ints (pad 1024)
    int*   edge_idx  = blockSums + 1024;          // E ints
    float* mask    = (float*)(edge_idx + E_TOT);  // E f
    float* a_nb    = mask + E_TOT;                // N_TOT f
    float* a_self  = a_nb + N_TOT;                // N_TOT f

    // Zero count + rowsum0 + rowsum1 + scal in one memset (~1.8MB)
    size_t zero_bytes = ((size_t)NSCAN + N_TOT + N_TOT + 16) * 4;
    hipMemsetAsync(count, 0, zero_bytes, stream);

    const int nDisBlocks = (N_TOT + 255) / 256;

    // ---- CSR build (row/col shared by both layers) ----
    hist_kernel<<<1024, 256, 0, stream>>>(row, count, E_TOT);
    scan_phase1<<<SCAN_BLOCKS, 256, 0, stream>>>(count, blockSums);
    scan_phase2<<<1, 256, 0, stream>>>(blockSums, SCAN_BLOCKS);
    scan_phase3<<<SCAN_BLOCKS, 256, 0, stream>>>(count, blockSums, start, cursor);
    scatter_kernel<<<1024, 256, 0, stream>>>(row, cursor, edge_idx, E_TOT);

    // ---- Layer 0 ----
    node_scalars_kernel<<<768, 256, 0, stream>>>(features, W_nb0, b_nb0, W_self0, b_self0,
                                                 W_att0, a_nb, a_self, N_TOT);
    edge_pass_a_kernel<<<2048, 256, 0, stream>>>(row, col, u0, a_nb, a_self, b_att0, temp,
                                                 mask, rowsum0, &scal[2], E_TOT);
    dis_kernel<<<nDisBlocks, 256, 0, stream>>>(rowsum0, N_TOT);
    edge_gather_kernel<<<2048, 256, 0, stream>>>(col, edge_idx, start, mask, rowsum0,
                                                 features, x1, N_TOT);

    // ---- Layer 1 ----
    node_scalars_kernel<<<768, 256, 0, stream>>>(x1, W_nb1, b_nb1, W_self1, b_self1,
                                                 W_att1, a_nb, a_self, N_TOT);
    edge_pass_a_kernel<<<2048, 256, 0, stream>>>(row, col, u1, a_nb, a_self, b_att1, temp,
                                                 mask, rowsum1, &scal[3], E_TOT);
    dis_kernel<<<nDisBlocks, 256, 0, stream>>>(rowsum1, N_TOT);
    edge_gather_kernel<<<2048, 256, 0, stream>>>(col, edge_idx, start, mask, rowsum1,
                                                 x1, x2, N_TOT);

    // ---- Losses ----
    bpr_kernel<<<64, 256, 0, stream>>>(features, x1, x2, users, items, negs, &scal[0], B_TOT);
    reg_kernel<<<1, 256, 0, stream>>>(W_nb0, b_nb0, W_self0, b_self0, W_att0, b_att0,
                                      W_nb1, b_nb1, W_self1, b_self1, W_att1, b_att1, &scal[1]);
    finalize_kernel<<<1, 1, 0, stream>>>(scal, out);
}

// Round 4
// 553.310 us; speedup vs baseline: 2.7945x; 1.3622x over previous
//
#include <hip/hip_runtime.h>
#include <hip/hip_bf16.h>

#define N_TOT   150000
#define N_USER  100000
#define E_TOT   1000000
#define B_TOT   4096
#define D_DIM   64

#define NSCAN       (N_TOT + 1)
#define SCAN_CHUNK  1024
#define SCAN_BLOCKS ((NSCAN + SCAN_CHUNK - 1) / SCAN_CHUNK)   // 147

// ---------------------------------------------------------------------------
// Per-node attention scalars: a_nb[v] = relu(x[v]@Wn+bn) . Wa[0:64]
//                             a_self[v] = relu(x[v]@Ws+bs) . Wa[64:128]
// One wave per node; weight columns in VGPRs; x-row via wave-uniform pointer.
// ---------------------------------------------------------------------------
__global__ __launch_bounds__(256, 3)
void node_scalars_kernel(const float* __restrict__ x,
                         const float* __restrict__ Wn, const float* __restrict__ bn,
                         const float* __restrict__ Ws, const float* __restrict__ bs,
                         const float* __restrict__ Wa,
                         float* __restrict__ a_nb, float* __restrict__ a_self,
                         int nNodes)
{
    const int lane   = threadIdx.x & 63;
    const int wave   = (blockIdx.x * blockDim.x + threadIdx.x) >> 6;
    const int nWaves = (gridDim.x * blockDim.x) >> 6;

    float wn[64], wsr[64];
    #pragma unroll
    for (int k = 0; k < 64; ++k) wn[k]  = Wn[k * 64 + lane];
    #pragma unroll
    for (int k = 0; k < 64; ++k) wsr[k] = Ws[k * 64 + lane];
    const float waT = Wa[lane];
    const float waB = Wa[64 + lane];
    const float bnl = bn[lane];
    const float bsl = bs[lane];

    for (int v = wave; v < nNodes; v += nWaves) {
        const int vu = __builtin_amdgcn_readfirstlane(v);
        const float* __restrict__ xr = x + (size_t)vu * 64;
        float hn = bnl, hs = bsl;
        #pragma unroll
        for (int k = 0; k < 64; ++k) {
            float xk = xr[k];
            hn = fmaf(xk, wn[k],  hn);
            hs = fmaf(xk, wsr[k], hs);
        }
        hn = fmaxf(hn, 0.0f) * waT;
        hs = fmaxf(hs, 0.0f) * waB;
        #pragma unroll
        for (int off = 32; off; off >>= 1) {
            hn += __shfl_xor(hn, off);
            hs += __shfl_xor(hs, off);
        }
        if (lane == 0) { a_nb[vu] = hn; a_self[vu] = hs; }
    }
}

// ---------------------------------------------------------------------------
// CSR build
// ---------------------------------------------------------------------------
__global__ void hist_kernel(const int* __restrict__ row, int* __restrict__ count, int nE)
{
    for (int e = blockIdx.x * blockDim.x + threadIdx.x; e < nE; e += gridDim.x * blockDim.x)
        atomicAdd(&count[row[e]], 1);
}

__global__ void scan_phase1(const int* __restrict__ count, int* __restrict__ blockSums)
{
    __shared__ int red[256];
    int base = blockIdx.x * SCAN_CHUNK;
    int s = 0;
    for (int i = threadIdx.x; i < SCAN_CHUNK; i += 256) {
        int idx = base + i;
        s += (idx < NSCAN) ? count[idx] : 0;
    }
    red[threadIdx.x] = s;
    __syncthreads();
    for (int st = 128; st > 0; st >>= 1) {
        if (threadIdx.x < st) red[threadIdx.x] += red[threadIdx.x + st];
        __syncthreads();
    }
    if (threadIdx.x == 0) blockSums[blockIdx.x] = red[0];
}

__global__ void scan_phase2(int* __restrict__ blockSums, int n)
{
    __shared__ int sh[256];
    int t = threadIdx.x;
    int v = (t < n) ? blockSums[t] : 0;
    sh[t] = v;
    __syncthreads();
    for (int off = 1; off < 256; off <<= 1) {
        int x = sh[t];
        if (t >= off) x += sh[t - off];
        __syncthreads();
        sh[t] = x;
        __syncthreads();
    }
    if (t < n) blockSums[t] = sh[t] - v;   // exclusive
}

__global__ void scan_phase3(const int* __restrict__ count, const int* __restrict__ blockSums,
                            int* __restrict__ start, int* __restrict__ cursor)
{
    __shared__ int sh[256];
    int base = blockIdx.x * SCAN_CHUNK;
    int t = threadIdx.x;
    int v[4];
    int s = 0;
    #pragma unroll
    for (int k = 0; k < 4; ++k) {
        int idx = base + t * 4 + k;
        v[k] = (idx < NSCAN) ? count[idx] : 0;
        s += v[k];
    }
    int orig = s;
    sh[t] = s;
    __syncthreads();
    for (int off = 1; off < 256; off <<= 1) {
        int x = sh[t];
        if (t >= off) x += sh[t - off];
        __syncthreads();
        sh[t] = x;
        __syncthreads();
    }
    int pre = sh[t] - orig + blockSums[blockIdx.x];
    #pragma unroll
    for (int k = 0; k < 4; ++k) {
        int idx = base + t * 4 + k;
        if (idx < NSCAN) { start[idx] = pre; cursor[idx] = pre; }
        pre += v[k];
    }
}

// scatter: perm[e] = CSR position of edge e (coalesced write);
//          colsorted[pos] = col[e] (random write, done once — col is layer-invariant)
__global__ void scatter_kernel(const int* __restrict__ row, const int* __restrict__ col,
                               int* __restrict__ cursor,
                               int* __restrict__ perm, int* __restrict__ colsorted, int nE)
{
    for (int e = blockIdx.x * blockDim.x + threadIdx.x; e < nE; e += gridDim.x * blockDim.x) {
        int pos = atomicAdd(&cursor[row[e]], 1);
        perm[e] = pos;
        colsorted[pos] = col[e];
    }
}

// ---------------------------------------------------------------------------
// Edge pass A: mask (written in CSR order via perm), rowsum, l0 partial sum
// ---------------------------------------------------------------------------
__global__ void edge_pass_a_kernel(const int* __restrict__ row, const int* __restrict__ col,
                                   const float* __restrict__ u,
                                   const float* __restrict__ a_nb, const float* __restrict__ a_self,
                                   const float* __restrict__ ba_p, const float* __restrict__ temp_p,
                                   const int* __restrict__ perm,
                                   float* __restrict__ msorted, float* __restrict__ rowsum,
                                   float* __restrict__ l0_accum, int nE)
{
    const float ba   = ba_p[0];
    const float t    = temp_p[0];
    const float invt = 1.0f / t;
    const float lt   = logf(0.45f / 1.05f);   // log(-GAMMA/ZETA)
    const float shift = t * lt;

    float l0local = 0.0f;
    for (int e = blockIdx.x * blockDim.x + threadIdx.x; e < nE; e += gridDim.x * blockDim.x) {
        int r = row[e], c = col[e];
        float la = a_nb[r] + a_self[c] + ba;
        float uu = u[e];
        float noise = logf(uu) - log1pf(-uu);
        float gate  = 1.0f / (1.0f + expf(-(noise + la) * invt));
        float m = fminf(fmaxf(gate * 1.5f - 0.45f, 0.0f), 1.0f); // ZETA-GAMMA=1.5, GAMMA=-0.45
        msorted[perm[e]] = m;
        if (m > 0.0f) unsafeAtomicAdd(&rowsum[r], m);
        l0local += 1.0f / (1.0f + expf(-(la - shift)));
    }

    __shared__ float red[256];
    red[threadIdx.x] = l0local;
    __syncthreads();
    for (int s = 128; s > 0; s >>= 1) {
        if (threadIdx.x < s) red[threadIdx.x] += red[threadIdx.x + s];
        __syncthreads();
    }
    if (threadIdx.x == 0) unsafeAtomicAdd(l0_accum, red[0]);
}

// ---------------------------------------------------------------------------
// rowsum -> d_inv_sqrt in place
// ---------------------------------------------------------------------------
__global__ void dis_kernel(float* __restrict__ rs, int n)
{
    int i = blockIdx.x * blockDim.x + threadIdx.x;
    if (i < n) {
        float v = rs[i] + 1e-6f;
        float d = 1.0f / sqrtf(v);
        rs[i] = fminf(d, 10.0f);
    }
}

// ---------------------------------------------------------------------------
// Edge gather: xn[r] = dis[r] * sum_j msorted[j]*dis[c_j]*x[c_j]
// CSR-ordered msorted/colsorted -> sequential uniform loads; 4-way unroll
// gives 4 independent x-row gathers in flight.
// ---------------------------------------------------------------------------
__global__ void edge_gather_kernel(const float* __restrict__ ms, const int* __restrict__ cs,
                                   const int* __restrict__ start,
                                   const float* __restrict__ dis,
                                   const float* __restrict__ x, float* __restrict__ xn, int nNodes)
{
    const int lane   = threadIdx.x & 63;
    const int wave   = (blockIdx.x * blockDim.x + threadIdx.x) >> 6;
    const int nWaves = (gridDim.x * blockDim.x) >> 6;

    for (int r = wave; r < nNodes; r += nWaves) {
        const int ru = __builtin_amdgcn_readfirstlane(r);
        int js = __builtin_amdgcn_readfirstlane(start[ru]);
        int je = __builtin_amdgcn_readfirstlane(start[ru + 1]);
        float acc = 0.0f;
        int j = js;
        for (; j + 4 <= je; j += 4) {
            float m0 = ms[j],     m1 = ms[j + 1], m2 = ms[j + 2], m3 = ms[j + 3];
            int   c0 = cs[j],     c1 = cs[j + 1], c2 = cs[j + 2], c3 = cs[j + 3];
            if (m0 > 0.0f) acc = fmaf(m0 * dis[c0], x[(size_t)c0 * 64 + lane], acc);
            if (m1 > 0.0f) acc = fmaf(m1 * dis[c1], x[(size_t)c1 * 64 + lane], acc);
            if (m2 > 0.0f) acc = fmaf(m2 * dis[c2], x[(size_t)c2 * 64 + lane], acc);
            if (m3 > 0.0f) acc = fmaf(m3 * dis[c3], x[(size_t)c3 * 64 + lane], acc);
        }
        for (; j < je; ++j) {
            float m = ms[j];
            if (m > 0.0f) {
                int c = cs[j];
                acc = fmaf(m * dis[c], x[(size_t)c * 64 + lane], acc);
            }
        }
        xn[(size_t)ru * 64 + lane] = acc * dis[ru];
    }
}

// ---------------------------------------------------------------------------
// BPR loss partial sum: one wave per batch element
// ---------------------------------------------------------------------------
__global__ void bpr_kernel(const float* __restrict__ f, const float* __restrict__ x1,
                           const float* __restrict__ x2,
                           const int* __restrict__ users, const int* __restrict__ items,
                           const int* __restrict__ negs,
                           float* __restrict__ bpr_accum, int B)
{
    const int lane   = threadIdx.x & 63;
    const int wave   = (blockIdx.x * blockDim.x + threadIdx.x) >> 6;
    const int nWaves = (gridDim.x * blockDim.x) >> 6;

    float local = 0.0f;
    for (int b = wave; b < B; b += nWaves) {
        int ui = users[b] * 64;
        int pi = (N_USER + items[b]) * 64;
        int ni = (N_USER + negs[b]) * 64;
        float a = f[ui + lane] + x1[ui + lane] + x2[ui + lane];
        float p = f[pi + lane] + x1[pi + lane] + x2[pi + lane];
        float n = f[ni + lane] + x1[ni + lane] + x2[ni + lane];
        float ps = a * p, ns = a * n;
        #pragma unroll
        for (int off = 32; off; off >>= 1) {
            ps += __shfl_xor(ps, off);
            ns += __shfl_xor(ns, off);
        }
        if (lane == 0) {
            float s = 1.0f / (1.0f + expf(-(ps - ns)));
            local += -logf(s + 1e-5f);
        }
    }
    if (lane == 0) unsafeAtomicAdd(bpr_accum, local);
}

// ---------------------------------------------------------------------------
// L2 regularization on params
// ---------------------------------------------------------------------------
__global__ void reg_kernel(const float* __restrict__ w0, const float* __restrict__ b0,
                           const float* __restrict__ w1, const float* __restrict__ b1,
                           const float* __restrict__ wa0, const float* __restrict__ ba0,
                           const float* __restrict__ w2, const float* __restrict__ b2,
                           const float* __restrict__ w3, const float* __restrict__ b3,
                           const float* __restrict__ wa1, const float* __restrict__ ba1,
                           float* __restrict__ accum)
{
    int t = threadIdx.x;
    float s = 0.0f;
    for (int i = t; i < 4096; i += 256)
        s += w0[i]*w0[i] + w1[i]*w1[i] + w2[i]*w2[i] + w3[i]*w3[i];
    for (int i = t; i < 64; i += 256)
        s += b0[i]*b0[i] + b1[i]*b1[i] + b2[i]*b2[i] + b3[i]*b3[i];
    for (int i = t; i < 128; i += 256)
        s += wa0[i]*wa0[i] + wa1[i]*wa1[i];
    if (t == 0) s += ba0[0]*ba0[0] + ba1[0]*ba1[0];

    __shared__ float red[256];
    red[t] = s;
    __syncthreads();
    for (int st = 128; st > 0; st >>= 1) {
        if (t < st) red[t] += red[t + st];
        __syncthreads();
    }
    if (t == 0) accum[0] = red[0];
}

// ---------------------------------------------------------------------------
// Final combine: bpr + reg + l0
// ---------------------------------------------------------------------------
__global__ void finalize_kernel(const float* __restrict__ scal, float* __restrict__ out)
{
    float bpr = scal[0] / (float)B_TOT;
    float reg = scal[1] * 1e-4f;
    float l0  = (scal[2] + scal[3]) * (1e-4f / (float)E_TOT);
    out[0] = bpr + reg + l0;
}

extern "C" void kernel_launch(void* const* d_in, const int* in_sizes, int n_in,
                              void* d_out, int out_size, void* d_ws, size_t ws_size,
                              hipStream_t stream)
{
    const float* features = (const float*)d_in[0];
    const int*   row      = (const int*)d_in[1];
    const int*   col      = (const int*)d_in[2];
    const int*   users    = (const int*)d_in[3];
    const int*   items    = (const int*)d_in[4];
    const int*   negs     = (const int*)d_in[5];
    const float* u0       = (const float*)d_in[6];
    const float* u1       = (const float*)d_in[7];
    const float* temp     = (const float*)d_in[8];
    const float* W_nb0    = (const float*)d_in[9];
    const float* b_nb0    = (const float*)d_in[10];
    const float* W_self0  = (const float*)d_in[11];
    const float* b_self0  = (const float*)d_in[12];
    const float* W_att0   = (const float*)d_in[13];
    const float* b_att0   = (const float*)d_in[14];
    const float* W_nb1    = (const float*)d_in[15];
    const float* b_nb1    = (const float*)d_in[16];
    const float* W_self1  = (const float*)d_in[17];
    const float* b_self1  = (const float*)d_in[18];
    const float* W_att1   = (const float*)d_in[19];
    const float* b_att1   = (const float*)d_in[20];
    float* out = (float*)d_out;

    // ---- Workspace layout (element offsets), ~93 MB total ----
    float* ws = (float*)d_ws;
    float* x1      = ws;                          // N*64 f
    float* x2      = x1 + (size_t)N_TOT * 64;     // N*64 f
    // zeroed block:
    int*   count   = (int*)(x2 + (size_t)N_TOT * 64);  // NSCAN
    float* rowsum0 = (float*)(count + NSCAN);     // N_TOT
    float* rowsum1 = rowsum0 + N_TOT;             // N_TOT
    float* scal    = rowsum1 + N_TOT;             // 16
    // end zeroed block
    int*   start     = (int*)(scal + 16);         // NSCAN
    int*   cursor    = start + NSCAN;             // NSCAN
    int*   blockSums = cursor + NSCAN;            // 1024
    int*   perm      = blockSums + 1024;          // E
    int*   colsorted = perm + E_TOT;              // E
    float* msorted   = (float*)(colsorted + E_TOT); // E
    float* a_nb    = msorted + E_TOT;             // N_TOT
    float* a_self  = a_nb + N_TOT;                // N_TOT

    size_t zero_bytes = ((size_t)NSCAN + N_TOT + N_TOT + 16) * 4;
    hipMemsetAsync(count, 0, zero_bytes, stream);

    const int nDisBlocks = (N_TOT + 255) / 256;

    // ---- CSR build (row/col shared by both layers) ----
    hist_kernel<<<1024, 256, 0, stream>>>(row, count, E_TOT);
    scan_phase1<<<SCAN_BLOCKS, 256, 0, stream>>>(count, blockSums);
    scan_phase2<<<1, 256, 0, stream>>>(blockSums, SCAN_BLOCKS);
    scan_phase3<<<SCAN_BLOCKS, 256, 0, stream>>>(count, blockSums, start, cursor);
    scatter_kernel<<<1024, 256, 0, stream>>>(row, col, cursor, perm, colsorted, E_TOT);

    // ---- Layer 0 ----
    node_scalars_kernel<<<768, 256, 0, stream>>>(features, W_nb0, b_nb0, W_self0, b_self0,
                                                 W_att0, a_nb, a_self, N_TOT);
    edge_pass_a_kernel<<<2048, 256, 0, stream>>>(row, col, u0, a_nb, a_self, b_att0, temp,
                                                 perm, msorted, rowsum0, &scal[2], E_TOT);
    dis_kernel<<<nDisBlocks, 256, 0, stream>>>(rowsum0, N_TOT);
    edge_gather_kernel<<<2048, 256, 0, stream>>>(msorted, colsorted, start, rowsum0,
                                                 features, x1, N_TOT);

    // ---- Layer 1 ----
    node_scalars_kernel<<<768, 256, 0, stream>>>(x1, W_nb1, b_nb1, W_self1, b_self1,
                                                 W_att1, a_nb, a_self, N_TOT);
    edge_pass_a_kernel<<<2048, 256, 0, stream>>>(row, col, u1, a_nb, a_self, b_att1, temp,
                                                 perm, msorted, rowsum1, &scal[3], E_TOT);
    dis_kernel<<<nDisBlocks, 256, 0, stream>>>(rowsum1, N_TOT);
    edge_gather_kernel<<<2048, 256, 0, stream>>>(msorted, colsorted, start, rowsum1,
                                                 x1, x2, N_TOT);

    // ---- Losses ----
    bpr_kernel<<<64, 256, 0, stream>>>(features, x1, x2, users, items, negs, &scal[0], B_TOT);
    reg_kernel<<<1, 256, 0, stream>>>(W_nb0, b_nb0, W_self0, b_self0, W_att0, b_att0,
                                      W_nb1, b_nb1, W_self1, b_self1, W_att1, b_att1, &scal[1]);
    finalize_kernel<<<1, 1, 0, stream>>>(scal, out);
}

// Round 5
// 490.938 us; speedup vs baseline: 3.1495x; 1.1270x over previous
//
#include <hip/hip_runtime.h>
#include <hip/hip_bf16.h>

#define N_TOT   150000
#define N_USER  100000
#define E_TOT   1000000
#define B_TOT   4096
#define D_DIM   64

#define NSCAN       (N_TOT + 1)
#define SCAN_CHUNK  1024
#define SCAN_BLOCKS ((NSCAN + SCAN_CHUNK - 1) / SCAN_CHUNK)   // 147

// ---------------------------------------------------------------------------
// Per-node attention scalars, THREAD-per-node version:
//   a_nb[v]   = relu(x[v]@Wn+bn) . Wa[0:64]
//   a_self[v] = relu(x[v]@Ws+bs) . Wa[64:128]
// h[64] lives in VGPRs (compile-time indexed). Weights read through the
// wave-uniform pointer -> scalar (SMEM) loads, amortized over 64 nodes/wave.
// Dot with Wa is thread-local; zero cross-lane ops.
// ---------------------------------------------------------------------------
__global__ __launch_bounds__(256, 4)
void node_scalars_kernel(const float* __restrict__ x,
                         const float* __restrict__ Wn, const float* __restrict__ bn,
                         const float* __restrict__ Ws, const float* __restrict__ bs,
                         const float* __restrict__ Wa,
                         float* __restrict__ a_nb, float* __restrict__ a_self,
                         int nNodes)
{
    const int v = blockIdx.x * 256 + threadIdx.x;
    if (v >= nNodes) return;

    const float4* __restrict__ xv4 = (const float4*)(x + (size_t)v * 64);

    float h[64];

    // ---- pass 1: h = x @ Wn + bn ----
    #pragma unroll
    for (int d = 0; d < 64; ++d) h[d] = bn[d];
    for (int kk = 0; kk < 16; ++kk) {
        float4 xk = xv4[kk];
        const float* __restrict__ wrow = Wn + (size_t)kk * 256;   // rows 4kk..4kk+3
        #pragma unroll
        for (int d = 0; d < 64; ++d) {
            float acc = h[d];
            acc = fmaf(xk.x, wrow[d],       acc);
            acc = fmaf(xk.y, wrow[64 + d],  acc);
            acc = fmaf(xk.z, wrow[128 + d], acc);
            acc = fmaf(xk.w, wrow[192 + d], acc);
            h[d] = acc;
        }
    }
    float an = 0.0f;
    #pragma unroll
    for (int d = 0; d < 64; ++d) an = fmaf(fmaxf(h[d], 0.0f), Wa[d], an);

    // ---- pass 2: h = x @ Ws + bs ----
    #pragma unroll
    for (int d = 0; d < 64; ++d) h[d] = bs[d];
    for (int kk = 0; kk < 16; ++kk) {
        float4 xk = xv4[kk];
        const float* __restrict__ wrow = Ws + (size_t)kk * 256;
        #pragma unroll
        for (int d = 0; d < 64; ++d) {
            float acc = h[d];
            acc = fmaf(xk.x, wrow[d],       acc);
            acc = fmaf(xk.y, wrow[64 + d],  acc);
            acc = fmaf(xk.z, wrow[128 + d], acc);
            acc = fmaf(xk.w, wrow[192 + d], acc);
            h[d] = acc;
        }
    }
    float as = 0.0f;
    #pragma unroll
    for (int d = 0; d < 64; ++d) as = fmaf(fmaxf(h[d], 0.0f), Wa[64 + d], as);

    a_nb[v]   = an;
    a_self[v] = as;
}

// ---------------------------------------------------------------------------
// CSR build
// ---------------------------------------------------------------------------
__global__ void hist_kernel(const int* __restrict__ row, int* __restrict__ count, int nE)
{
    for (int e = blockIdx.x * blockDim.x + threadIdx.x; e < nE; e += gridDim.x * blockDim.x)
        atomicAdd(&count[row[e]], 1);
}

__global__ void scan_phase1(const int* __restrict__ count, int* __restrict__ blockSums)
{
    __shared__ int red[256];
    int base = blockIdx.x * SCAN_CHUNK;
    int s = 0;
    for (int i = threadIdx.x; i < SCAN_CHUNK; i += 256) {
        int idx = base + i;
        s += (idx < NSCAN) ? count[idx] : 0;
    }
    red[threadIdx.x] = s;
    __syncthreads();
    for (int st = 128; st > 0; st >>= 1) {
        if (threadIdx.x < st) red[threadIdx.x] += red[threadIdx.x + st];
        __syncthreads();
    }
    if (threadIdx.x == 0) blockSums[blockIdx.x] = red[0];
}

__global__ void scan_phase2(int* __restrict__ blockSums, int n)
{
    __shared__ int sh[256];
    int t = threadIdx.x;
    int v = (t < n) ? blockSums[t] : 0;
    sh[t] = v;
    __syncthreads();
    for (int off = 1; off < 256; off <<= 1) {
        int x = sh[t];
        if (t >= off) x += sh[t - off];
        __syncthreads();
        sh[t] = x;
        __syncthreads();
    }
    if (t < n) blockSums[t] = sh[t] - v;   // exclusive
}

__global__ void scan_phase3(const int* __restrict__ count, const int* __restrict__ blockSums,
                            int* __restrict__ start, int* __restrict__ cursor)
{
    __shared__ int sh[256];
    int base = blockIdx.x * SCAN_CHUNK;
    int t = threadIdx.x;
    int v[4];
    int s = 0;
    #pragma unroll
    for (int k = 0; k < 4; ++k) {
        int idx = base + t * 4 + k;
        v[k] = (idx < NSCAN) ? count[idx] : 0;
        s += v[k];
    }
    int orig = s;
    sh[t] = s;
    __syncthreads();
    for (int off = 1; off < 256; off <<= 1) {
        int x = sh[t];
        if (t >= off) x += sh[t - off];
        __syncthreads();
        sh[t] = x;
        __syncthreads();
    }
    int pre = sh[t] - orig + blockSums[blockIdx.x];
    #pragma unroll
    for (int k = 0; k < 4; ++k) {
        int idx = base + t * 4 + k;
        if (idx < NSCAN) { start[idx] = pre; cursor[idx] = pre; }
        pre += v[k];
    }
}

// scatter: perm[e] = CSR position of edge e (coalesced write);
//          colsorted[pos] = col[e] (random write, done once — col is layer-invariant)
__global__ void scatter_kernel(const int* __restrict__ row, const int* __restrict__ col,
                               int* __restrict__ cursor,
                               int* __restrict__ perm, int* __restrict__ colsorted, int nE)
{
    for (int e = blockIdx.x * blockDim.x + threadIdx.x; e < nE; e += gridDim.x * blockDim.x) {
        int pos = atomicAdd(&cursor[row[e]], 1);
        perm[e] = pos;
        colsorted[pos] = col[e];
    }
}

// ---------------------------------------------------------------------------
// Edge pass A: mask (written in CSR order via perm), rowsum, l0 partial sum
// ---------------------------------------------------------------------------
__global__ void edge_pass_a_kernel(const int* __restrict__ row, const int* __restrict__ col,
                                   const float* __restrict__ u,
                                   const float* __restrict__ a_nb, const float* __restrict__ a_self,
                                   const float* __restrict__ ba_p, const float* __restrict__ temp_p,
                                   const int* __restrict__ perm,
                                   float* __restrict__ msorted, float* __restrict__ rowsum,
                                   float* __restrict__ l0_accum, int nE)
{
    const float ba   = ba_p[0];
    const float t    = temp_p[0];
    const float invt = 1.0f / t;
    const float lt   = logf(0.45f / 1.05f);   // log(-GAMMA/ZETA)
    const float shift = t * lt;

    float l0local = 0.0f;
    for (int e = blockIdx.x * blockDim.x + threadIdx.x; e < nE; e += gridDim.x * blockDim.x) {
        int r = row[e], c = col[e];
        float la = a_nb[r] + a_self[c] + ba;
        float uu = u[e];
        float noise = logf(uu) - log1pf(-uu);
        float gate  = 1.0f / (1.0f + expf(-(noise + la) * invt));
        float m = fminf(fmaxf(gate * 1.5f - 0.45f, 0.0f), 1.0f); // ZETA-GAMMA=1.5, GAMMA=-0.45
        msorted[perm[e]] = m;
        if (m > 0.0f) unsafeAtomicAdd(&rowsum[r], m);
        l0local += 1.0f / (1.0f + expf(-(la - shift)));
    }

    __shared__ float red[256];
    red[threadIdx.x] = l0local;
    __syncthreads();
    for (int s = 128; s > 0; s >>= 1) {
        if (threadIdx.x < s) red[threadIdx.x] += red[threadIdx.x + s];
        __syncthreads();
    }
    if (threadIdx.x == 0) unsafeAtomicAdd(l0_accum, red[0]);
}

// ---------------------------------------------------------------------------
// rowsum -> d_inv_sqrt in place
// ---------------------------------------------------------------------------
__global__ void dis_kernel(float* __restrict__ rs, int n)
{
    int i = blockIdx.x * blockDim.x + threadIdx.x;
    if (i < n) {
        float v = rs[i] + 1e-6f;
        float d = 1.0f / sqrtf(v);
        rs[i] = fminf(d, 10.0f);
    }
}

// ---------------------------------------------------------------------------
// Edge gather: xn[r] = dis[r] * sum_j msorted[j]*dis[c_j]*x[c_j]
// CSR-ordered msorted/colsorted -> sequential uniform loads; 4-way unroll
// gives 4 independent x-row gathers in flight.
// ---------------------------------------------------------------------------
__global__ void edge_gather_kernel(const float* __restrict__ ms, const int* __restrict__ cs,
                                   const int* __restrict__ start,
                                   const float* __restrict__ dis,
                                   const float* __restrict__ x, float* __restrict__ xn, int nNodes)
{
    const int lane   = threadIdx.x & 63;
    const int wave   = (blockIdx.x * blockDim.x + threadIdx.x) >> 6;
    const int nWaves = (gridDim.x * blockDim.x) >> 6;

    for (int r = wave; r < nNodes; r += nWaves) {
        const int ru = __builtin_amdgcn_readfirstlane(r);
        int js = __builtin_amdgcn_readfirstlane(start[ru]);
        int je = __builtin_amdgcn_readfirstlane(start[ru + 1]);
        float acc = 0.0f;
        int j = js;
        for (; j + 4 <= je; j += 4) {
            float m0 = ms[j],     m1 = ms[j + 1], m2 = ms[j + 2], m3 = ms[j + 3];
            int   c0 = cs[j],     c1 = cs[j + 1], c2 = cs[j + 2], c3 = cs[j + 3];
            if (m0 > 0.0f) acc = fmaf(m0 * dis[c0], x[(size_t)c0 * 64 + lane], acc);
            if (m1 > 0.0f) acc = fmaf(m1 * dis[c1], x[(size_t)c1 * 64 + lane], acc);
            if (m2 > 0.0f) acc = fmaf(m2 * dis[c2], x[(size_t)c2 * 64 + lane], acc);
            if (m3 > 0.0f) acc = fmaf(m3 * dis[c3], x[(size_t)c3 * 64 + lane], acc);
        }
        for (; j < je; ++j) {
            float m = ms[j];
            if (m > 0.0f) {
                int c = cs[j];
                acc = fmaf(m * dis[c], x[(size_t)c * 64 + lane], acc);
            }
        }
        xn[(size_t)ru * 64 + lane] = acc * dis[ru];
    }
}

// ---------------------------------------------------------------------------
// BPR loss partial sum: one wave per batch element
// ---------------------------------------------------------------------------
__global__ void bpr_kernel(const float* __restrict__ f, const float* __restrict__ x1,
                           const float* __restrict__ x2,
                           const int* __restrict__ users, const int* __restrict__ items,
                           const int* __restrict__ negs,
                           float* __restrict__ bpr_accum, int B)
{
    const int lane   = threadIdx.x & 63;
    const int wave   = (blockIdx.x * blockDim.x + threadIdx.x) >> 6;
    const int nWaves = (gridDim.x * blockDim.x) >> 6;

    float local = 0.0f;
    for (int b = wave; b < B; b += nWaves) {
        int ui = users[b] * 64;
        int pi = (N_USER + items[b]) * 64;
        int ni = (N_USER + negs[b]) * 64;
        float a = f[ui + lane] + x1[ui + lane] + x2[ui + lane];
        float p = f[pi + lane] + x1[pi + lane] + x2[pi + lane];
        float n = f[ni + lane] + x1[ni + lane] + x2[ni + lane];
        float ps = a * p, ns = a * n;
        #pragma unroll
        for (int off = 32; off; off >>= 1) {
            ps += __shfl_xor(ps, off);
            ns += __shfl_xor(ns, off);
        }
        if (lane == 0) {
            float s = 1.0f / (1.0f + expf(-(ps - ns)));
            local += -logf(s + 1e-5f);
        }
    }
    if (lane == 0) unsafeAtomicAdd(bpr_accum, local);
}

// ---------------------------------------------------------------------------
// L2 regularization on params
// ---------------------------------------------------------------------------
__global__ void reg_kernel(const float* __restrict__ w0, const float* __restrict__ b0,
                           const float* __restrict__ w1, const float* __restrict__ b1,
                           const float* __restrict__ wa0, const float* __restrict__ ba0,
                           const float* __restrict__ w2, const float* __restrict__ b2,
                           const float* __restrict__ w3, const float* __restrict__ b3,
                           const float* __restrict__ wa1, const float* __restrict__ ba1,
                           float* __restrict__ accum)
{
    int t = threadIdx.x;
    float s = 0.0f;
    for (int i = t; i < 4096; i += 256)
        s += w0[i]*w0[i] + w1[i]*w1[i] + w2[i]*w2[i] + w3[i]*w3[i];
    for (int i = t; i < 64; i += 256)
        s += b0[i]*b0[i] + b1[i]*b1[i] + b2[i]*b2[i] + b3[i]*b3[i];
    for (int i = t; i < 128; i += 256)
        s += wa0[i]*wa0[i] + wa1[i]*wa1[i];
    if (t == 0) s += ba0[0]*ba0[0] + ba1[0]*ba1[0];

    __shared__ float red[256];
    red[t] = s;
    __syncthreads();
    for (int st = 128; st > 0; st >>= 1) {
        if (t < st) red[t] += red[t + st];
        __syncthreads();
    }
    if (t == 0) accum[0] = red[0];
}

// ---------------------------------------------------------------------------
// Final combine: bpr + reg + l0
// ---------------------------------------------------------------------------
__global__ void finalize_kernel(const float* __restrict__ scal, float* __restrict__ out)
{
    float bpr = scal[0] / (float)B_TOT;
    float reg = scal[1] * 1e-4f;
    float l0  = (scal[2] + scal[3]) * (1e-4f / (float)E_TOT);
    out[0] = bpr + reg + l0;
}

extern "C" void kernel_launch(void* const* d_in, const int* in_sizes, int n_in,
                              void* d_out, int out_size, void* d_ws, size_t ws_size,
                              hipStream_t stream)
{
    const float* features = (const float*)d_in[0];
    const int*   row      = (const int*)d_in[1];
    const int*   col      = (const int*)d_in[2];
    const int*   users    = (const int*)d_in[3];
    const int*   items    = (const int*)d_in[4];
    const int*   negs     = (const int*)d_in[5];
    const float* u0       = (const float*)d_in[6];
    const float* u1       = (const float*)d_in[7];
    const float* temp     = (const float*)d_in[8];
    const float* W_nb0    = (const float*)d_in[9];
    const float* b_nb0    = (const float*)d_in[10];
    const float* W_self0  = (const float*)d_in[11];
    const float* b_self0  = (const float*)d_in[12];
    const float* W_att0   = (const float*)d_in[13];
    const float* b_att0   = (const float*)d_in[14];
    const float* W_nb1    = (const float*)d_in[15];
    const float* b_nb1    = (const float*)d_in[16];
    const float* W_self1  = (const float*)d_in[17];
    const float* b_self1  = (const float*)d_in[18];
    const float* W_att1   = (const float*)d_in[19];
    const float* b_att1   = (const float*)d_in[20];
    float* out = (float*)d_out;

    // ---- Workspace layout (element offsets), ~93 MB total ----
    float* ws = (float*)d_ws;
    float* x1      = ws;                          // N*64 f
    float* x2      = x1 + (size_t)N_TOT * 64;     // N*64 f
    // zeroed block:
    int*   count   = (int*)(x2 + (size_t)N_TOT * 64);  // NSCAN
    float* rowsum0 = (float*)(count + NSCAN);     // N_TOT
    float* rowsum1 = rowsum0 + N_TOT;             // N_TOT
    float* scal    = rowsum1 + N_TOT;             // 16
    // end zeroed block
    int*   start     = (int*)(scal + 16);         // NSCAN
    int*   cursor    = start + NSCAN;             // NSCAN
    int*   blockSums = cursor + NSCAN;            // 1024
    int*   perm      = blockSums + 1024;          // E
    int*   colsorted = perm + E_TOT;              // E
    float* msorted   = (float*)(colsorted + E_TOT); // E
    float* a_nb    = msorted + E_TOT;             // N_TOT
    float* a_self  = a_nb + N_TOT;                // N_TOT

    size_t zero_bytes = ((size_t)NSCAN + N_TOT + N_TOT + 16) * 4;
    hipMemsetAsync(count, 0, zero_bytes, stream);

    const int nDisBlocks = (N_TOT + 255) / 256;
    const int nNsBlocks  = (N_TOT + 255) / 256;   // thread-per-node

    // ---- CSR build (row/col shared by both layers) ----
    hist_kernel<<<1024, 256, 0, stream>>>(row, count, E_TOT);
    scan_phase1<<<SCAN_BLOCKS, 256, 0, stream>>>(count, blockSums);
    scan_phase2<<<1, 256, 0, stream>>>(blockSums, SCAN_BLOCKS);
    scan_phase3<<<SCAN_BLOCKS, 256, 0, stream>>>(count, blockSums, start, cursor);
    scatter_kernel<<<1024, 256, 0, stream>>>(row, col, cursor, perm, colsorted, E_TOT);

    // ---- Layer 0 ----
    node_scalars_kernel<<<nNsBlocks, 256, 0, stream>>>(features, W_nb0, b_nb0, W_self0, b_self0,
                                                       W_att0, a_nb, a_self, N_TOT);
    edge_pass_a_kernel<<<2048, 256, 0, stream>>>(row, col, u0, a_nb, a_self, b_att0, temp,
                                                 perm, msorted, rowsum0, &scal[2], E_TOT);
    dis_kernel<<<nDisBlocks, 256, 0, stream>>>(rowsum0, N_TOT);
    edge_gather_kernel<<<2048, 256, 0, stream>>>(msorted, colsorted, start, rowsum0,
                                                 features, x1, N_TOT);

    // ---- Layer 1 ----
    node_scalars_kernel<<<nNsBlocks, 256, 0, stream>>>(x1, W_nb1, b_nb1, W_self1, b_self1,
                                                       W_att1, a_nb, a_self, N_TOT);
    edge_pass_a_kernel<<<2048, 256, 0, stream>>>(row, col, u1, a_nb, a_self, b_att1, temp,
                                                 perm, msorted, rowsum1, &scal[3], E_TOT);
    dis_kernel<<<nDisBlocks, 256, 0, stream>>>(rowsum1, N_TOT);
    edge_gather_kernel<<<2048, 256, 0, stream>>>(msorted, colsorted, start, rowsum1,
                                                 x1, x2, N_TOT);

    // ---- Losses ----
    bpr_kernel<<<64, 256, 0, stream>>>(features, x1, x2, users, items, negs, &scal[0], B_TOT);
    reg_kernel<<<1, 256, 0, stream>>>(W_nb0, b_nb0, W_self0, b_self0, W_att0, b_att0,
                                      W_nb1, b_nb1, W_self1, b_self1, W_att1, b_att1, &scal[1]);
    finalize_kernel<<<1, 1, 0, stream>>>(scal, out);
}

// Round 6
// 463.249 us; speedup vs baseline: 3.3378x; 1.0598x over previous
//
#include <hip/hip_runtime.h>
#include <hip/hip_bf16.h>

#define N_TOT   150000
#define N_USER  100000
#define E_TOT   1000000
#define B_TOT   4096
#define D_DIM   64

#define NSCAN       (N_TOT + 1)
#define NSCAN_PAD   150016          // NSCAN rounded up to multiple of 8
#define SCAN_CHUNK  1024
#define SCAN_BLOCKS ((NSCAN + SCAN_CHUNK - 1) / SCAN_CHUNK)   // 147

// ---------------------------------------------------------------------------
// Per-node attention scalars, thread-per-node:
//   a_nb[v]   = relu(x[v]@Wn+bn) . Wa[0:64]
//   a_self[v] = relu(x[v]@Ws+bs) . Wa[64:128]
// h[64] in VGPRs; weight rows via wave-uniform pointer (SMEM path).
// ---------------------------------------------------------------------------
__global__ __launch_bounds__(256, 4)
void node_scalars_kernel(const float* __restrict__ x,
                         const float* __restrict__ Wn, const float* __restrict__ bn,
                         const float* __restrict__ Ws, const float* __restrict__ bs,
                         const float* __restrict__ Wa,
                         float* __restrict__ a_nb, float* __restrict__ a_self,
                         int nNodes)
{
    const int v = blockIdx.x * 256 + threadIdx.x;
    if (v >= nNodes) return;

    const float4* __restrict__ xv4 = (const float4*)(x + (size_t)v * 64);

    float h[64];

    // ---- pass 1: h = x @ Wn + bn ----
    #pragma unroll
    for (int d = 0; d < 64; ++d) h[d] = bn[d];
    for (int kk = 0; kk < 16; ++kk) {
        float4 xk = xv4[kk];
        const float* __restrict__ wrow = Wn + (size_t)kk * 256;
        #pragma unroll
        for (int d = 0; d < 64; ++d) {
            float acc = h[d];
            acc = fmaf(xk.x, wrow[d],       acc);
            acc = fmaf(xk.y, wrow[64 + d],  acc);
            acc = fmaf(xk.z, wrow[128 + d], acc);
            acc = fmaf(xk.w, wrow[192 + d], acc);
            h[d] = acc;
        }
    }
    float an = 0.0f;
    #pragma unroll
    for (int d = 0; d < 64; ++d) an = fmaf(fmaxf(h[d], 0.0f), Wa[d], an);

    // ---- pass 2: h = x @ Ws + bs ----
    #pragma unroll
    for (int d = 0; d < 64; ++d) h[d] = bs[d];
    for (int kk = 0; kk < 16; ++kk) {
        float4 xk = xv4[kk];
        const float* __restrict__ wrow = Ws + (size_t)kk * 256;
        #pragma unroll
        for (int d = 0; d < 64; ++d) {
            float acc = h[d];
            acc = fmaf(xk.x, wrow[d],       acc);
            acc = fmaf(xk.y, wrow[64 + d],  acc);
            acc = fmaf(xk.z, wrow[128 + d], acc);
            acc = fmaf(xk.w, wrow[192 + d], acc);
            h[d] = acc;
        }
    }
    float as = 0.0f;
    #pragma unroll
    for (int d = 0; d < 64; ++d) as = fmaf(fmaxf(h[d], 0.0f), Wa[64 + d], as);

    a_nb[v]   = an;
    a_self[v] = as;
}

// ---------------------------------------------------------------------------
// CSR build
// ---------------------------------------------------------------------------
__global__ void hist_kernel(const int* __restrict__ row, int* __restrict__ count, int nE)
{
    for (int e = blockIdx.x * blockDim.x + threadIdx.x; e < nE; e += gridDim.x * blockDim.x)
        atomicAdd(&count[row[e]], 1);
}

__global__ void scan_phase1(const int* __restrict__ count, int* __restrict__ blockSums)
{
    __shared__ int red[256];
    int base = blockIdx.x * SCAN_CHUNK;
    int s = 0;
    for (int i = threadIdx.x; i < SCAN_CHUNK; i += 256) {
        int idx = base + i;
        s += (idx < NSCAN) ? count[idx] : 0;
    }
    red[threadIdx.x] = s;
    __syncthreads();
    for (int st = 128; st > 0; st >>= 1) {
        if (threadIdx.x < st) red[threadIdx.x] += red[threadIdx.x + st];
        __syncthreads();
    }
    if (threadIdx.x == 0) blockSums[blockIdx.x] = red[0];
}

__global__ void scan_phase2(int* __restrict__ blockSums, int n)
{
    __shared__ int sh[256];
    int t = threadIdx.x;
    int v = (t < n) ? blockSums[t] : 0;
    sh[t] = v;
    __syncthreads();
    for (int off = 1; off < 256; off <<= 1) {
        int x = sh[t];
        if (t >= off) x += sh[t - off];
        __syncthreads();
        sh[t] = x;
        __syncthreads();
    }
    if (t < n) blockSums[t] = sh[t] - v;   // exclusive
}

__global__ void scan_phase3(const int* __restrict__ count, const int* __restrict__ blockSums,
                            int* __restrict__ start, int* __restrict__ cursor)
{
    __shared__ int sh[256];
    int base = blockIdx.x * SCAN_CHUNK;
    int t = threadIdx.x;
    int v[4];
    int s = 0;
    #pragma unroll
    for (int k = 0; k < 4; ++k) {
        int idx = base + t * 4 + k;
        v[k] = (idx < NSCAN) ? count[idx] : 0;
        s += v[k];
    }
    int orig = s;
    sh[t] = s;
    __syncthreads();
    for (int off = 1; off < 256; off <<= 1) {
        int x = sh[t];
        if (t >= off) x += sh[t - off];
        __syncthreads();
        sh[t] = x;
        __syncthreads();
    }
    int pre = sh[t] - orig + blockSums[blockIdx.x];
    #pragma unroll
    for (int k = 0; k < 4; ++k) {
        int idx = base + t * 4 + k;
        if (idx < NSCAN) { start[idx] = pre; cursor[idx] = pre; }
        pre += v[k];
    }
}

// scatter: single random 8B store per edge carries BOTH col and edge id.
__global__ void scatter_kernel(const int* __restrict__ row, const int* __restrict__ col,
                               int* __restrict__ cursor, int2* __restrict__ ei, int nE)
{
    for (int e = blockIdx.x * blockDim.x + threadIdx.x; e < nE; e += gridDim.x * blockDim.x) {
        int pos = atomicAdd(&cursor[row[e]], 1);
        ei[pos] = make_int2(col[e], e);
    }
}

// ---------------------------------------------------------------------------
// Edge pass A, node-parallel (thread per node): walks the node's CSR segment,
// sequential msorted write, register rowsum (no atomics), fused d_inv_sqrt.
// ---------------------------------------------------------------------------
__global__ __launch_bounds__(256)
void edge_pass_a_kernel(const int2* __restrict__ ei, const int* __restrict__ start,
                        const float* __restrict__ u,
                        const float* __restrict__ a_nb, const float* __restrict__ a_self,
                        const float* __restrict__ ba_p, const float* __restrict__ temp_p,
                        float* __restrict__ msorted, float* __restrict__ dis,
                        float* __restrict__ l0_accum, int nNodes)
{
    const float ba   = ba_p[0];
    const float t    = temp_p[0];
    const float invt = 1.0f / t;
    const float lt   = logf(0.45f / 1.05f);   // log(-GAMMA/ZETA)
    const float shift = t * lt;

    const int r = blockIdx.x * 256 + threadIdx.x;
    float l0local = 0.0f;

    if (r < nNodes) {
        const int js = start[r], je = start[r + 1];
        const float la_base = a_nb[r] + ba;
        float rs = 0.0f;
        for (int j = js; j < je; ++j) {
            int2 p = ei[j];                       // {col, e}
            float la = la_base + a_self[p.x];
            float uu = u[p.y];
            float noise = logf(uu) - log1pf(-uu);
            float gate  = 1.0f / (1.0f + expf(-(noise + la) * invt));
            float m = fminf(fmaxf(gate * 1.5f - 0.45f, 0.0f), 1.0f);
            msorted[j] = m;
            rs += m;
            l0local += 1.0f / (1.0f + expf(-(la - shift)));
        }
        dis[r] = fminf(1.0f / sqrtf(rs + 1e-6f), 10.0f);
    }

    __shared__ float red[256];
    red[threadIdx.x] = l0local;
    __syncthreads();
    for (int s = 128; s > 0; s >>= 1) {
        if (threadIdx.x < s) red[threadIdx.x] += red[threadIdx.x + s];
        __syncthreads();
    }
    if (threadIdx.x == 0) unsafeAtomicAdd(l0_accum, red[0]);
}

// ---------------------------------------------------------------------------
// Edge gather: xn[r] = dis[r] * sum_j msorted[j]*dis[c_j]*x[c_j]
// One wave per node, lane = feature dim; sequential ms/ei, 4-way unroll.
// ---------------------------------------------------------------------------
__global__ void edge_gather_kernel(const float* __restrict__ ms, const int2* __restrict__ ei,
                                   const int* __restrict__ start,
                                   const float* __restrict__ dis,
                                   const float* __restrict__ x, float* __restrict__ xn, int nNodes)
{
    const int lane   = threadIdx.x & 63;
    const int wave   = (blockIdx.x * blockDim.x + threadIdx.x) >> 6;
    const int nWaves = (gridDim.x * blockDim.x) >> 6;

    for (int r = wave; r < nNodes; r += nWaves) {
        const int ru = __builtin_amdgcn_readfirstlane(r);
        int js = __builtin_amdgcn_readfirstlane(start[ru]);
        int je = __builtin_amdgcn_readfirstlane(start[ru + 1]);
        float acc = 0.0f;
        int j = js;
        for (; j + 4 <= je; j += 4) {
            float m0 = ms[j],   m1 = ms[j+1], m2 = ms[j+2], m3 = ms[j+3];
            int   c0 = ei[j].x, c1 = ei[j+1].x, c2 = ei[j+2].x, c3 = ei[j+3].x;
            if (m0 > 0.0f) acc = fmaf(m0 * dis[c0], x[(size_t)c0 * 64 + lane], acc);
            if (m1 > 0.0f) acc = fmaf(m1 * dis[c1], x[(size_t)c1 * 64 + lane], acc);
            if (m2 > 0.0f) acc = fmaf(m2 * dis[c2], x[(size_t)c2 * 64 + lane], acc);
            if (m3 > 0.0f) acc = fmaf(m3 * dis[c3], x[(size_t)c3 * 64 + lane], acc);
        }
        for (; j < je; ++j) {
            float m = ms[j];
            if (m > 0.0f) {
                int c = ei[j].x;
                acc = fmaf(m * dis[c], x[(size_t)c * 64 + lane], acc);
            }
        }
        xn[(size_t)ru * 64 + lane] = acc * dis[ru];
    }
}

// ---------------------------------------------------------------------------
// BPR loss partial sum: one wave per batch element
// ---------------------------------------------------------------------------
__global__ void bpr_kernel(const float* __restrict__ f, const float* __restrict__ x1,
                           const float* __restrict__ x2,
                           const int* __restrict__ users, const int* __restrict__ items,
                           const int* __restrict__ negs,
                           float* __restrict__ bpr_accum, int B)
{
    const int lane   = threadIdx.x & 63;
    const int wave   = (blockIdx.x * blockDim.x + threadIdx.x) >> 6;
    const int nWaves = (gridDim.x * blockDim.x) >> 6;

    float local = 0.0f;
    for (int b = wave; b < B; b += nWaves) {
        int ui = users[b] * 64;
        int pi = (N_USER + items[b]) * 64;
        int ni = (N_USER + negs[b]) * 64;
        float a = f[ui + lane] + x1[ui + lane] + x2[ui + lane];
        float p = f[pi + lane] + x1[pi + lane] + x2[pi + lane];
        float n = f[ni + lane] + x1[ni + lane] + x2[ni + lane];
        float ps = a * p, ns = a * n;
        #pragma unroll
        for (int off = 32; off; off >>= 1) {
            ps += __shfl_xor(ps, off);
            ns += __shfl_xor(ns, off);
        }
        if (lane == 0) {
            float s = 1.0f / (1.0f + expf(-(ps - ns)));
            local += -logf(s + 1e-5f);
        }
    }
    if (lane == 0) unsafeAtomicAdd(bpr_accum, local);
}

// ---------------------------------------------------------------------------
// L2 regularization on params
// ---------------------------------------------------------------------------
__global__ void reg_kernel(const float* __restrict__ w0, const float* __restrict__ b0,
                           const float* __restrict__ w1, const float* __restrict__ b1,
                           const float* __restrict__ wa0, const float* __restrict__ ba0,
                           const float* __restrict__ w2, const float* __restrict__ b2,
                           const float* __restrict__ w3, const float* __restrict__ b3,
                           const float* __restrict__ wa1, const float* __restrict__ ba1,
                           float* __restrict__ accum)
{
    int t = threadIdx.x;
    float s = 0.0f;
    for (int i = t; i < 4096; i += 256)
        s += w0[i]*w0[i] + w1[i]*w1[i] + w2[i]*w2[i] + w3[i]*w3[i];
    for (int i = t; i < 64; i += 256)
        s += b0[i]*b0[i] + b1[i]*b1[i] + b2[i]*b2[i] + b3[i]*b3[i];
    for (int i = t; i < 128; i += 256)
        s += wa0[i]*wa0[i] + wa1[i]*wa1[i];
    if (t == 0) s += ba0[0]*ba0[0] + ba1[0]*ba1[0];

    __shared__ float red[256];
    red[t] = s;
    __syncthreads();
    for (int st = 128; st > 0; st >>= 1) {
        if (t < st) red[t] += red[t + st];
        __syncthreads();
    }
    if (t == 0) accum[0] = red[0];
}

// ---------------------------------------------------------------------------
// Final combine: bpr + reg + l0
// ---------------------------------------------------------------------------
__global__ void finalize_kernel(const float* __restrict__ scal, float* __restrict__ out)
{
    float bpr = scal[0] / (float)B_TOT;
    float reg = scal[1] * 1e-4f;
    float l0  = (scal[2] + scal[3]) * (1e-4f / (float)E_TOT);
    out[0] = bpr + reg + l0;
}

extern "C" void kernel_launch(void* const* d_in, const int* in_sizes, int n_in,
                              void* d_out, int out_size, void* d_ws, size_t ws_size,
                              hipStream_t stream)
{
    const float* features = (const float*)d_in[0];
    const int*   row      = (const int*)d_in[1];
    const int*   col      = (const int*)d_in[2];
    const int*   users    = (const int*)d_in[3];
    const int*   items    = (const int*)d_in[4];
    const int*   negs     = (const int*)d_in[5];
    const float* u0       = (const float*)d_in[6];
    const float* u1       = (const float*)d_in[7];
    const float* temp     = (const float*)d_in[8];
    const float* W_nb0    = (const float*)d_in[9];
    const float* b_nb0    = (const float*)d_in[10];
    const float* W_self0  = (const float*)d_in[11];
    const float* b_self0  = (const float*)d_in[12];
    const float* W_att0   = (const float*)d_in[13];
    const float* b_att0   = (const float*)d_in[14];
    const float* W_nb1    = (const float*)d_in[15];
    const float* b_nb1    = (const float*)d_in[16];
    const float* W_self1  = (const float*)d_in[17];
    const float* b_self1  = (const float*)d_in[18];
    const float* W_att1   = (const float*)d_in[19];
    const float* b_att1   = (const float*)d_in[20];
    float* out = (float*)d_out;

    // ---- Workspace layout (4B element offsets), ~92 MB total ----
    float* ws = (float*)d_ws;
    float* x1      = ws;                           // N*64
    float* x2      = x1 + (size_t)N_TOT * 64;      // N*64
    // zeroed block: count + scal
    int*   count   = (int*)(x2 + (size_t)N_TOT * 64);  // NSCAN_PAD
    float* scal    = (float*)(count + NSCAN_PAD);  // 16
    // end zeroed block
    int*   start     = (int*)(scal + 16);          // NSCAN_PAD
    int*   cursor    = start + NSCAN_PAD;          // NSCAN_PAD
    int*   blockSums = cursor + NSCAN_PAD;         // 1024
    int2*  ei        = (int2*)(blockSums + 1024);  // E int2 (8B-aligned)
    float* msorted   = (float*)(ei + E_TOT);       // E
    float* dis       = msorted + E_TOT;            // N_TOT (reused both layers)
    float* a_nb      = dis + N_TOT;                // N_TOT
    float* a_self    = a_nb + N_TOT;               // N_TOT

    size_t zero_bytes = ((size_t)NSCAN_PAD + 16) * 4;
    hipMemsetAsync(count, 0, zero_bytes, stream);

    const int nNodeBlocks = (N_TOT + 255) / 256;   // 586

    // ---- CSR build (row/col shared by both layers) ----
    hist_kernel<<<1024, 256, 0, stream>>>(row, count, E_TOT);
    scan_phase1<<<SCAN_BLOCKS, 256, 0, stream>>>(count, blockSums);
    scan_phase2<<<1, 256, 0, stream>>>(blockSums, SCAN_BLOCKS);
    scan_phase3<<<SCAN_BLOCKS, 256, 0, stream>>>(count, blockSums, start, cursor);
    scatter_kernel<<<1024, 256, 0, stream>>>(row, col, cursor, ei, E_TOT);

    // ---- Layer 0 ----
    node_scalars_kernel<<<nNodeBlocks, 256, 0, stream>>>(features, W_nb0, b_nb0, W_self0, b_self0,
                                                         W_att0, a_nb, a_self, N_TOT);
    edge_pass_a_kernel<<<nNodeBlocks, 256, 0, stream>>>(ei, start, u0, a_nb, a_self, b_att0, temp,
                                                        msorted, dis, &scal[2], N_TOT);
    edge_gather_kernel<<<2048, 256, 0, stream>>>(msorted, ei, start, dis, features, x1, N_TOT);

    // ---- Layer 1 ----
    node_scalars_kernel<<<nNodeBlocks, 256, 0, stream>>>(x1, W_nb1, b_nb1, W_self1, b_self1,
                                                         W_att1, a_nb, a_self, N_TOT);
    edge_pass_a_kernel<<<nNodeBlocks, 256, 0, stream>>>(ei, start, u1, a_nb, a_self, b_att1, temp,
                                                        msorted, dis, &scal[3], N_TOT);
    edge_gather_kernel<<<2048, 256, 0, stream>>>(msorted, ei, start, dis, x1, x2, N_TOT);

    // ---- Losses ----
    bpr_kernel<<<64, 256, 0, stream>>>(features, x1, x2, users, items, negs, &scal[0], B_TOT);
    reg_kernel<<<1, 256, 0, stream>>>(W_nb0, b_nb0, W_self0, b_self0, W_att0, b_att0,
                                      W_nb1, b_nb1, W_self1, b_self1, W_att1, b_att1, &scal[1]);
    finalize_kernel<<<1, 1, 0, stream>>>(scal, out);
}

// Round 7
// 380.898 us; speedup vs baseline: 4.0594x; 1.2162x over previous
//
#include <hip/hip_runtime.h>
#include <hip/hip_bf16.h>

#define N_TOT   150000
#define N_USER  100000
#define E_TOT   1000000
#define B_TOT   4096
#define D_DIM   64

#define NSCAN_PAD   150016          // N_TOT+1 rounded up to multiple of 8
#define BKT_SHIFT   10
#define BKT_ROWS    (1 << BKT_SHIFT)                 // 1024 rows per bucket
#define NBKT        ((N_TOT + BKT_ROWS - 1) / BKT_ROWS)   // 147
#define BKT_CAP     8192            // expected ~6800 edges/bucket; 17 sigma headroom
#define BIN_CHUNK   4096
#define NBIN_BLOCKS ((E_TOT + BIN_CHUNK - 1) / BIN_CHUNK) // 245

// ---------------------------------------------------------------------------
// Per-node attention scalars, thread-per-node:
//   a_nb[v]   = relu(x[v]@Wn+bn) . Wa[0:64]
//   a_self[v] = relu(x[v]@Ws+bs) . Wa[64:128]
// h[64] in VGPRs; weight rows via wave-uniform pointer (SMEM path).
// ---------------------------------------------------------------------------
__global__ __launch_bounds__(256, 4)
void node_scalars_kernel(const float* __restrict__ x,
                         const float* __restrict__ Wn, const float* __restrict__ bn,
                         const float* __restrict__ Ws, const float* __restrict__ bs,
                         const float* __restrict__ Wa,
                         float* __restrict__ a_nb, float* __restrict__ a_self,
                         int nNodes)
{
    const int v = blockIdx.x * 256 + threadIdx.x;
    if (v >= nNodes) return;

    const float4* __restrict__ xv4 = (const float4*)(x + (size_t)v * 64);

    float h[64];

    // ---- pass 1: h = x @ Wn + bn ----
    #pragma unroll
    for (int d = 0; d < 64; ++d) h[d] = bn[d];
    for (int kk = 0; kk < 16; ++kk) {
        float4 xk = xv4[kk];
        const float* __restrict__ wrow = Wn + (size_t)kk * 256;
        #pragma unroll
        for (int d = 0; d < 64; ++d) {
            float acc = h[d];
            acc = fmaf(xk.x, wrow[d],       acc);
            acc = fmaf(xk.y, wrow[64 + d],  acc);
            acc = fmaf(xk.z, wrow[128 + d], acc);
            acc = fmaf(xk.w, wrow[192 + d], acc);
            h[d] = acc;
        }
    }
    float an = 0.0f;
    #pragma unroll
    for (int d = 0; d < 64; ++d) an = fmaf(fmaxf(h[d], 0.0f), Wa[d], an);

    // ---- pass 2: h = x @ Ws + bs ----
    #pragma unroll
    for (int d = 0; d < 64; ++d) h[d] = bs[d];
    for (int kk = 0; kk < 16; ++kk) {
        float4 xk = xv4[kk];
        const float* __restrict__ wrow = Ws + (size_t)kk * 256;
        #pragma unroll
        for (int d = 0; d < 64; ++d) {
            float acc = h[d];
            acc = fmaf(xk.x, wrow[d],       acc);
            acc = fmaf(xk.y, wrow[64 + d],  acc);
            acc = fmaf(xk.z, wrow[128 + d], acc);
            acc = fmaf(xk.w, wrow[192 + d], acc);
            h[d] = acc;
        }
    }
    float as = 0.0f;
    #pragma unroll
    for (int d = 0; d < 64; ++d) as = fmaf(fmaxf(h[d], 0.0f), Wa[64 + d], as);

    a_nb[v]   = an;
    a_self[v] = as;
}

// ---------------------------------------------------------------------------
// Phase 1: bin edges into NBKT coarse buckets (1024 rows each). LDS histogram
// + one global reservation per (block,bucket) -> writes are ~220B contiguous
// runs per bucket (near-full 64B lines), instead of 1M isolated 8B stores.
// tmp[b*BKT_CAP + i] = {row, e}.
// ---------------------------------------------------------------------------
__global__ __launch_bounds__(256)
void bin_kernel(const int* __restrict__ row, int* __restrict__ bcnt,
                int2* __restrict__ tmp, int nE)
{
    __shared__ int cnt[NBKT];
    __shared__ int base[NBKT];
    for (int i = threadIdx.x; i < NBKT; i += 256) cnt[i] = 0;
    __syncthreads();

    const int e0 = blockIdx.x * BIN_CHUNK + threadIdx.x;
    int r[16];
    #pragma unroll
    for (int k = 0; k < 16; ++k) {
        int e = e0 + k * 256;
        r[k] = (e < nE) ? row[e] : -1;
        if (r[k] >= 0) atomicAdd(&cnt[r[k] >> BKT_SHIFT], 1);
    }
    __syncthreads();

    for (int i = threadIdx.x; i < NBKT; i += 256) {
        int c = cnt[i];
        base[i] = c ? atomicAdd(&bcnt[i], c) : 0;
        cnt[i] = 0;                         // reuse as intra-block offset
    }
    __syncthreads();

    #pragma unroll
    for (int k = 0; k < 16; ++k) {
        if (r[k] >= 0) {
            int b   = r[k] >> BKT_SHIFT;
            int loc = atomicAdd(&cnt[b], 1);
            tmp[(size_t)b * BKT_CAP + base[b] + loc] = make_int2(r[k], e0 + k * 256);
        }
    }
}

// ---------------------------------------------------------------------------
// Exclusive scan over the 147 bucket counts -> absolute CSR base per bucket.
// ---------------------------------------------------------------------------
__global__ void bucket_scan_kernel(const int* __restrict__ bcnt, int* __restrict__ bbase,
                                   int* __restrict__ start)
{
    __shared__ int sh[256];
    int t = threadIdx.x;
    int v = (t < NBKT) ? bcnt[t] : 0;
    sh[t] = v;
    __syncthreads();
    for (int off = 1; off < 256; off <<= 1) {
        int x = sh[t];
        if (t >= off) x += sh[t - off];
        __syncthreads();
        sh[t] = x;
        __syncthreads();
    }
    if (t <= NBKT) bbase[t] = (t == 0) ? 0 : sh[t - 1];
    if (t == 0) start[N_TOT] = E_TOT;
}

// ---------------------------------------------------------------------------
// Phase 2: one block per bucket. LDS counting-sort over the bucket's 1024
// rows produces start[] for those rows AND final CSR placement. All writes
// confined to the bucket's ~54KB region from a single CU -> L2 assembles
// full lines; HBM writeback ~= payload.
// ---------------------------------------------------------------------------
__global__ __launch_bounds__(256)
void scatter2_kernel(const int2* __restrict__ tmp, const int* __restrict__ bcnt,
                     const int* __restrict__ bbase, const int* __restrict__ col,
                     int* __restrict__ start, int2* __restrict__ ei)
{
    __shared__ int pref[BKT_ROWS];
    __shared__ int wsum[256];

    const int b     = blockIdx.x;
    const int rlo   = b << BKT_SHIFT;
    const int nrows = min(BKT_ROWS, N_TOT - rlo);
    const int cntb  = bcnt[b];
    const int baseb = bbase[b];
    const int t     = threadIdx.x;
    const int2* __restrict__ bkt = tmp + (size_t)b * BKT_CAP;

    for (int i = t; i < BKT_ROWS; i += 256) pref[i] = 0;
    __syncthreads();

    // count rows in this bucket
    for (int j = t; j < cntb; j += 256)
        atomicAdd(&pref[bkt[j].x - rlo], 1);
    __syncthreads();

    // exclusive scan over 1024 row counts (each thread owns 4)
    const int base4 = t * 4;
    int v0 = pref[base4], v1 = pref[base4 + 1], v2 = pref[base4 + 2], v3 = pref[base4 + 3];
    int s = v0 + v1 + v2 + v3;
    wsum[t] = s;
    __syncthreads();
    for (int off = 1; off < 256; off <<= 1) {
        int x = wsum[t];
        if (t >= off) x += wsum[t - off];
        __syncthreads();
        wsum[t] = x;
        __syncthreads();
    }
    const int pre = wsum[t] - s;
    const int p0 = pre, p1 = pre + v0, p2 = pre + v0 + v1, p3 = pre + v0 + v1 + v2;

    if (base4     < nrows) start[rlo + base4]     = baseb + p0;
    if (base4 + 1 < nrows) start[rlo + base4 + 1] = baseb + p1;
    if (base4 + 2 < nrows) start[rlo + base4 + 2] = baseb + p2;
    if (base4 + 3 < nrows) start[rlo + base4 + 3] = baseb + p3;

    // repurpose pref as running offsets (each thread rewrites its own 4 slots)
    pref[base4] = p0; pref[base4 + 1] = p1; pref[base4 + 2] = p2; pref[base4 + 3] = p3;
    __syncthreads();

    for (int j = t; j < cntb; j += 256) {
        int2 p  = bkt[j];
        int loc = atomicAdd(&pref[p.x - rlo], 1);
        ei[baseb + loc] = make_int2(col[p.y], p.y);
    }
}

// ---------------------------------------------------------------------------
// Edge pass A, node-parallel: sequential msorted write, register rowsum,
// fused d_inv_sqrt.
// ---------------------------------------------------------------------------
__global__ __launch_bounds__(256)
void edge_pass_a_kernel(const int2* __restrict__ ei, const int* __restrict__ start,
                        const float* __restrict__ u,
                        const float* __restrict__ a_nb, const float* __restrict__ a_self,
                        const float* __restrict__ ba_p, const float* __restrict__ temp_p,
                        float* __restrict__ msorted, float* __restrict__ dis,
                        float* __restrict__ l0_accum, int nNodes)
{
    const float ba   = ba_p[0];
    const float t    = temp_p[0];
    const float invt = 1.0f / t;
    const float lt   = logf(0.45f / 1.05f);   // log(-GAMMA/ZETA)
    const float shift = t * lt;

    const int r = blockIdx.x * 256 + threadIdx.x;
    float l0local = 0.0f;

    if (r < nNodes) {
        const int js = start[r], je = start[r + 1];
        const float la_base = a_nb[r] + ba;
        float rs = 0.0f;
        for (int j = js; j < je; ++j) {
            int2 p = ei[j];                       // {col, e}
            float la = la_base + a_self[p.x];
            float uu = u[p.y];
            float noise = logf(uu) - log1pf(-uu);
            float gate  = 1.0f / (1.0f + expf(-(noise + la) * invt));
            float m = fminf(fmaxf(gate * 1.5f - 0.45f, 0.0f), 1.0f);
            msorted[j] = m;
            rs += m;
            l0local += 1.0f / (1.0f + expf(-(la - shift)));
        }
        dis[r] = fminf(1.0f / sqrtf(rs + 1e-6f), 10.0f);
    }

    __shared__ float red[256];
    red[threadIdx.x] = l0local;
    __syncthreads();
    for (int s = 128; s > 0; s >>= 1) {
        if (threadIdx.x < s) red[threadIdx.x] += red[threadIdx.x + s];
        __syncthreads();
    }
    if (threadIdx.x == 0) unsafeAtomicAdd(l0_accum, red[0]);
}

// ---------------------------------------------------------------------------
// Edge gather: xn[r] = dis[r] * sum_j msorted[j]*dis[c_j]*x[c_j]
// One wave per node, lane = feature dim; sequential ms/ei, 4-way unroll.
// ---------------------------------------------------------------------------
__global__ void edge_gather_kernel(const float* __restrict__ ms, const int2* __restrict__ ei,
                                   const int* __restrict__ start,
                                   const float* __restrict__ dis,
                                   const float* __restrict__ x, float* __restrict__ xn, int nNodes)
{
    const int lane   = threadIdx.x & 63;
    const int wave   = (blockIdx.x * blockDim.x + threadIdx.x) >> 6;
    const int nWaves = (gridDim.x * blockDim.x) >> 6;

    for (int r = wave; r < nNodes; r += nWaves) {
        const int ru = __builtin_amdgcn_readfirstlane(r);
        int js = __builtin_amdgcn_readfirstlane(start[ru]);
        int je = __builtin_amdgcn_readfirstlane(start[ru + 1]);
        float acc = 0.0f;
        int j = js;
        for (; j + 4 <= je; j += 4) {
            float m0 = ms[j],   m1 = ms[j+1], m2 = ms[j+2], m3 = ms[j+3];
            int   c0 = ei[j].x, c1 = ei[j+1].x, c2 = ei[j+2].x, c3 = ei[j+3].x;
            if (m0 > 0.0f) acc = fmaf(m0 * dis[c0], x[(size_t)c0 * 64 + lane], acc);
            if (m1 > 0.0f) acc = fmaf(m1 * dis[c1], x[(size_t)c1 * 64 + lane], acc);
            if (m2 > 0.0f) acc = fmaf(m2 * dis[c2], x[(size_t)c2 * 64 + lane], acc);
            if (m3 > 0.0f) acc = fmaf(m3 * dis[c3], x[(size_t)c3 * 64 + lane], acc);
        }
        for (; j < je; ++j) {
            float m = ms[j];
            if (m > 0.0f) {
                int c = ei[j].x;
                acc = fmaf(m * dis[c], x[(size_t)c * 64 + lane], acc);
            }
        }
        xn[(size_t)ru * 64 + lane] = acc * dis[ru];
    }
}

// ---------------------------------------------------------------------------
// BPR loss partial sum: one wave per batch element
// ---------------------------------------------------------------------------
__global__ void bpr_kernel(const float* __restrict__ f, const float* __restrict__ x1,
                           const float* __restrict__ x2,
                           const int* __restrict__ users, const int* __restrict__ items,
                           const int* __restrict__ negs,
                           float* __restrict__ bpr_accum, int B)
{
    const int lane   = threadIdx.x & 63;
    const int wave   = (blockIdx.x * blockDim.x + threadIdx.x) >> 6;
    const int nWaves = (gridDim.x * blockDim.x) >> 6;

    float local = 0.0f;
    for (int b = wave; b < B; b += nWaves) {
        int ui = users[b] * 64;
        int pi = (N_USER + items[b]) * 64;
        int ni = (N_USER + negs[b]) * 64;
        float a = f[ui + lane] + x1[ui + lane] + x2[ui + lane];
        float p = f[pi + lane] + x1[pi + lane] + x2[pi + lane];
        float n = f[ni + lane] + x1[ni + lane] + x2[ni + lane];
        float ps = a * p, ns = a * n;
        #pragma unroll
        for (int off = 32; off; off >>= 1) {
            ps += __shfl_xor(ps, off);
            ns += __shfl_xor(ns, off);
        }
        if (lane == 0) {
            float s = 1.0f / (1.0f + expf(-(ps - ns)));
            local += -logf(s + 1e-5f);
        }
    }
    if (lane == 0) unsafeAtomicAdd(bpr_accum, local);
}

// ---------------------------------------------------------------------------
// L2 regularization on params
// ---------------------------------------------------------------------------
__global__ void reg_kernel(const float* __restrict__ w0, const float* __restrict__ b0,
                           const float* __restrict__ w1, const float* __restrict__ b1,
                           const float* __restrict__ wa0, const float* __restrict__ ba0,
                           const float* __restrict__ w2, const float* __restrict__ b2,
                           const float* __restrict__ w3, const float* __restrict__ b3,
                           const float* __restrict__ wa1, const float* __restrict__ ba1,
                           float* __restrict__ accum)
{
    int t = threadIdx.x;
    float s = 0.0f;
    for (int i = t; i < 4096; i += 256)
        s += w0[i]*w0[i] + w1[i]*w1[i] + w2[i]*w2[i] + w3[i]*w3[i];
    for (int i = t; i < 64; i += 256)
        s += b0[i]*b0[i] + b1[i]*b1[i] + b2[i]*b2[i] + b3[i]*b3[i];
    for (int i = t; i < 128; i += 256)
        s += wa0[i]*wa0[i] + wa1[i]*wa1[i];
    if (t == 0) s += ba0[0]*ba0[0] + ba1[0]*ba1[0];

    __shared__ float red[256];
    red[t] = s;
    __syncthreads();
    for (int st = 128; st > 0; st >>= 1) {
        if (t < st) red[t] += red[t + st];
        __syncthreads();
    }
    if (t == 0) accum[0] = red[0];
}

// ---------------------------------------------------------------------------
// Final combine: bpr + reg + l0
// ---------------------------------------------------------------------------
__global__ void finalize_kernel(const float* __restrict__ scal, float* __restrict__ out)
{
    float bpr = scal[0] / (float)B_TOT;
    float reg = scal[1] * 1e-4f;
    float l0  = (scal[2] + scal[3]) * (1e-4f / (float)E_TOT);
    out[0] = bpr + reg + l0;
}

extern "C" void kernel_launch(void* const* d_in, const int* in_sizes, int n_in,
                              void* d_out, int out_size, void* d_ws, size_t ws_size,
                              hipStream_t stream)
{
    const float* features = (const float*)d_in[0];
    const int*   row      = (const int*)d_in[1];
    const int*   col      = (const int*)d_in[2];
    const int*   users    = (const int*)d_in[3];
    const int*   items    = (const int*)d_in[4];
    const int*   negs     = (const int*)d_in[5];
    const float* u0       = (const float*)d_in[6];
    const float* u1       = (const float*)d_in[7];
    const float* temp     = (const float*)d_in[8];
    const float* W_nb0    = (const float*)d_in[9];
    const float* b_nb0    = (const float*)d_in[10];
    const float* W_self0  = (const float*)d_in[11];
    const float* b_self0  = (const float*)d_in[12];
    const float* W_att0   = (const float*)d_in[13];
    const float* b_att0   = (const float*)d_in[14];
    const float* W_nb1    = (const float*)d_in[15];
    const float* b_nb1    = (const float*)d_in[16];
    const float* W_self1  = (const float*)d_in[17];
    const float* b_self1  = (const float*)d_in[18];
    const float* W_att1   = (const float*)d_in[19];
    const float* b_att1   = (const float*)d_in[20];
    float* out = (float*)d_out;

    // ---- Workspace layout (4B element offsets), ~91 MB total ----
    float* ws = (float*)d_ws;
    float* x1      = ws;                           // N*64
    float* x2      = x1 + (size_t)N_TOT * 64;      // N*64
    int2*  tmp     = (int2*)x2;                    // ALIAS: NBKT*BKT_CAP int2 (9.6MB)
                                                   // dead before gather-L1 writes x2
    // zeroed block: scal + bcnt
    float* scal    = (float*)(x2 + (size_t)N_TOT * 64);  // 16
    int*   bcnt    = (int*)(scal + 16);            // NBKT (pad 160)
    // end zeroed block
    int*   bbase   = bcnt + 160;                   // NBKT+1 (pad 160)
    int*   start   = bbase + 160;                  // NSCAN_PAD
    int2*  ei      = (int2*)(start + NSCAN_PAD);   // E int2
    float* msorted = (float*)(ei + E_TOT);         // E
    float* dis     = msorted + E_TOT;              // N_TOT
    float* a_nb    = dis + N_TOT;                  // N_TOT
    float* a_self  = a_nb + N_TOT;                 // N_TOT

    hipMemsetAsync(scal, 0, (16 + 160) * sizeof(float), stream);

    const int nNodeBlocks = (N_TOT + 255) / 256;   // 586

    // ---- CSR build: bin -> bucket scan -> per-bucket counting-sort ----
    bin_kernel<<<NBIN_BLOCKS, 256, 0, stream>>>(row, bcnt, tmp, E_TOT);
    bucket_scan_kernel<<<1, 256, 0, stream>>>(bcnt, bbase, start);
    scatter2_kernel<<<NBKT, 256, 0, stream>>>(tmp, bcnt, bbase, col, start, ei);

    // ---- Layer 0 ----
    node_scalars_kernel<<<nNodeBlocks, 256, 0, stream>>>(features, W_nb0, b_nb0, W_self0, b_self0,
                                                         W_att0, a_nb, a_self, N_TOT);
    edge_pass_a_kernel<<<nNodeBlocks, 256, 0, stream>>>(ei, start, u0, a_nb, a_self, b_att0, temp,
                                                        msorted, dis, &scal[2], N_TOT);
    edge_gather_kernel<<<2048, 256, 0, stream>>>(msorted, ei, start, dis, features, x1, N_TOT);

    // ---- Layer 1 ----
    node_scalars_kernel<<<nNodeBlocks, 256, 0, stream>>>(x1, W_nb1, b_nb1, W_self1, b_self1,
                                                         W_att1, a_nb, a_self, N_TOT);
    edge_pass_a_kernel<<<nNodeBlocks, 256, 0, stream>>>(ei, start, u1, a_nb, a_self, b_att1, temp,
                                                        msorted, dis, &scal[3], N_TOT);
    edge_gather_kernel<<<2048, 256, 0, stream>>>(msorted, ei, start, dis, x1, x2, N_TOT);

    // ---- Losses ----
    bpr_kernel<<<64, 256, 0, stream>>>(features, x1, x2, users, items, negs, &scal[0], B_TOT);
    reg_kernel<<<1, 256, 0, stream>>>(W_nb0, b_nb0, W_self0, b_self0, W_att0, b_att0,
                                      W_nb1, b_nb1, W_self1, b_self1, W_att1, b_att1, &scal[1]);
    finalize_kernel<<<1, 1, 0, stream>>>(scal, out);
}